// Round 4
// baseline (244.734 us; speedup 1.0000x reference)
//
#include <hip/hip_runtime.h>

#define NBATCH 4096

typedef _Float16 f16;
typedef __attribute__((ext_vector_type(8))) _Float16 f16x8;
typedef __attribute__((ext_vector_type(4))) _Float16 f16x4;
typedef __attribute__((ext_vector_type(2))) _Float16 f16x2;
typedef __attribute__((ext_vector_type(4))) float f32x4;

__device__ __forceinline__ float lrelu(float x) { return x > 0.0f ? x : 0.2f * x; }
__device__ __forceinline__ float elu1(float x)  { return x > 0.0f ? x : __expf(x) - 1.0f; }

// W2 (128x128 f32 row-major) -> W2^T f16: w2t[n][k] = W2[k][n]
__global__ void w2t_prep(const float* __restrict__ W2, f16* __restrict__ w2t) {
    int idx = blockIdx.x * 256 + threadIdx.x;     // 16384
    int k = idx >> 7, n = idx & 127;              // coalesced read
    w2t[n * 128 + k] = (f16)W2[k * 128 + n];
}

// LDS layouts (XOR-swizzled, every 16B group aligned):
//   WhT[feat][node] 128x64 : off = f*64 + (((n>>3)^(f&7))<<3) + (n&7)
//   h1 [node][feat] 64x128 : off = n*128 + (((f>>3)^(n&15))<<3) + (f&7)
__device__ __forceinline__ int idxWh(int f, int n) { return f * 64  + ((((n >> 3) ^ (f & 7)))  << 3) + (n & 7); }
__device__ __forceinline__ int idxH (int n, int f) { return n * 128 + ((((f >> 3) ^ (n & 15))) << 3) + (f & 7); }

__global__ __launch_bounds__(256, 4)
void gat_kernel(const float* __restrict__ users,
                const float* __restrict__ W1,
                const float* __restrict__ a1,
                const float* __restrict__ a2,
                const f16* __restrict__ w2t,
                const float* __restrict__ mw1,
                const float* __restrict__ mb1,
                const float* __restrict__ mw2,
                const float* __restrict__ mb2,
                float* __restrict__ out)
{
    const int b = blockIdx.x;
    const int t = threadIdx.x;
    const int wave = t >> 6;
    const int lane = t & 63;
    const int lr = lane & 15;
    const int lq = lane >> 4;

    __shared__ f16 sWh[2][8192];      // hi/lo planes: Wh1T -> h1 -> Wh2T  (32 KB)
    __shared__ float sSi[64], sSj[64];
    __shared__ float sPoolW[4][128];  // pooling partials; reused as readout partials [8][32]
    __shared__ float sPool[128];
    __shared__ float sHid[32];
    __shared__ float sRaw[128];
    __shared__ float sSums[2];

    // ---- Phase B: Wh1 = users @ W1 (hi/lo into WhT) + fp32 scores si/sj fused ----
    {
        const int a = t >> 3;          // node pair (2a, 2a+1); 8 threads per pair
        const int fl = t & 7;          // f = fl + 8k  -> f&7 varies across lanes (bank spread)
        const int n0 = 2 * a;
        const float* ub = users + b * 192 + n0 * 3;
        float2 u01 = *(const float2*)(ub);
        float2 u23 = *(const float2*)(ub + 2);
        float2 u45 = *(const float2*)(ub + 4);
        const float x0 = u01.x, y0 = u01.y, z0 = u23.x;
        const float x1 = u23.y, y1 = u45.x, z1 = u45.y;
        float si0 = 0.f, sj0 = 0.f, si1 = 0.f, sj1 = 0.f;
        #pragma unroll
        for (int k = 0; k < 16; ++k) {
            const int f = fl + 8 * k;
            const float w0 = W1[f], w1 = W1[128 + f], w2 = W1[256 + f];
            const float v0 = fmaf(x0, w0, fmaf(y0, w1, z0 * w2));
            const float v1 = fmaf(x1, w0, fmaf(y1, w1, z1 * w2));
            si0 = fmaf(v0, a1[f], si0);       sj0 = fmaf(v0, a1[128 + f], sj0);
            si1 = fmaf(v1, a1[f], si1);       sj1 = fmaf(v1, a1[128 + f], sj1);
            const f16 h0 = (f16)v0, h1v = (f16)v1;
            const f16 l0 = (f16)(v0 - (float)h0), l1 = (f16)(v1 - (float)h1v);
            const int off = idxWh(f, n0);     // n0 even -> pair contiguous in same 8-group
            *(f16x2*)&sWh[0][off] = (f16x2){h0, h1v};
            *(f16x2*)&sWh[1][off] = (f16x2){l0, l1};
        }
        #pragma unroll
        for (int m = 1; m < 8; m <<= 1) {
            si0 += __shfl_xor(si0, m, 64);  sj0 += __shfl_xor(sj0, m, 64);
            si1 += __shfl_xor(si1, m, 64);  sj1 += __shfl_xor(sj1, m, 64);
        }
        if (fl == 0) {
            sSi[n0] = si0; sSi[n0 + 1] = si1;
            sSj[n0] = sj0; sSj[n0 + 1] = sj1;
        }
    }
    __syncthreads();

    for (int L = 0; L < 2; ++L) {
        if (L == 1) {
            // ---- Phase F: Wh2 = h1 @ W2 (A = h1 hi/lo LDS, B = w2t global/L1) ----
            __syncthreads();   // h1 stores visible
            const int row = wave * 16 + lr;
            f16x8 ahi[4], alo[4];
            #pragma unroll
            for (int ks = 0; ks < 4; ++ks) {
                const int off = row * 128 + ((((ks * 4 + lq) ^ (row & 15))) << 3);
                ahi[ks] = *(const f16x8*)&sWh[0][off];
                alo[ks] = *(const f16x8*)&sWh[1][off];
            }
            __syncthreads();   // all h1 reads done -> sWh free for Wh2T stores

            float a2f[8], a2s[8];
            #pragma unroll
            for (int nt = 0; nt < 8; ++nt) {
                a2f[nt] = a2[nt * 16 + lr];
                a2s[nt] = a2[128 + nt * 16 + lr];
            }
            f32x4 acc[8];
            #pragma unroll
            for (int nt = 0; nt < 8; ++nt) acc[nt] = (f32x4){0.f, 0.f, 0.f, 0.f};
            #pragma unroll
            for (int nt = 0; nt < 8; ++nt) {
                const f16* bp = w2t + (nt * 16 + lr) * 128 + lq * 8;
                #pragma unroll
                for (int ks = 0; ks < 4; ++ks) {
                    f16x8 bf = *(const f16x8*)(bp + ks * 32);
                    acc[nt] = __builtin_amdgcn_mfma_f32_16x16x32_f16(ahi[ks], bf, acc[nt], 0, 0, 0);
                    acc[nt] = __builtin_amdgcn_mfma_f32_16x16x32_f16(alo[ks], bf, acc[nt], 0, 0, 0);
                }
            }
            // fp32 scores from accumulators: si/sj for nodes wave*16+lq*4+r
            float sir[4] = {0.f, 0.f, 0.f, 0.f}, sjr[4] = {0.f, 0.f, 0.f, 0.f};
            #pragma unroll
            for (int nt = 0; nt < 8; ++nt) {
                #pragma unroll
                for (int r = 0; r < 4; ++r) {
                    sir[r] = fmaf(acc[nt][r], a2f[nt], sir[r]);
                    sjr[r] = fmaf(acc[nt][r], a2s[nt], sjr[r]);
                }
            }
            #pragma unroll
            for (int m = 1; m < 16; m <<= 1) {
                #pragma unroll
                for (int r = 0; r < 4; ++r) {
                    sir[r] += __shfl_xor(sir[r], m, 64);
                    sjr[r] += __shfl_xor(sjr[r], m, 64);
                }
            }
            // store Wh2T hi/lo (D: row=node=wave*16+lq*4+r, col=feat=nt*16+lr)
            #pragma unroll
            for (int nt = 0; nt < 8; ++nt) {
                const int feat = nt * 16 + lr;
                const int g = wave * 2 + (lq >> 1);
                const int base = feat * 64 + (((g ^ (feat & 7))) << 3) + ((lq & 1) * 4);
                f16x4 hv, lv;
                #pragma unroll
                for (int r = 0; r < 4; ++r) {
                    const float v = acc[nt][r];
                    const f16 hi = (f16)v;
                    hv[r] = hi;
                    lv[r] = (f16)(v - (float)hi);
                }
                *(f16x4*)&sWh[0][base] = hv;
                *(f16x4*)&sWh[1][base] = lv;
            }
            if (lr == 0) {
                #pragma unroll
                for (int r = 0; r < 4; ++r) {
                    const int n = wave * 16 + lq * 4 + r;
                    sSi[n] = sir[r];
                    sSj[n] = sjr[r];
                }
            }
            __syncthreads();
        }

        // ---- Phase E (fused softmax): h = elu(diag(inv) * P @ Wh) ----
        {
            const int row = wave * 16 + lr;          // A-fragment row
            const float si = sSi[row];
            float sjv[16];
            #pragma unroll
            for (int x = 0; x < 16; ++x)
                sjv[x] = sSj[(x >> 3) * 32 + lq * 8 + (x & 7)];
            float mj = sjv[0];
            #pragma unroll
            for (int x = 1; x < 16; ++x) mj = fmaxf(mj, sjv[x]);
            mj = fmaxf(mj, __shfl_xor(mj, 16, 64));
            mj = fmaxf(mj, __shfl_xor(mj, 32, 64));
            const float mi = lrelu(si + mj);         // lrelu monotone -> row max

            f16x8 ap[2];
            float lsum = 0.f;
            #pragma unroll
            for (int ks = 0; ks < 2; ++ks) {
                #pragma unroll
                for (int jj = 0; jj < 8; ++jj) {
                    const float p = __expf(lrelu(si + sjv[ks * 8 + jj]) - mi);
                    const f16 ph = (f16)p;
                    lsum += (float)ph;               // debiased denominator
                    ap[ks][jj] = ph;
                }
            }
            lsum += __shfl_xor(lsum, 16, 64);
            lsum += __shfl_xor(lsum, 32, 64);
            const float inv = 1.0f / lsum;

            f32x4 acc[8];
            #pragma unroll
            for (int nt = 0; nt < 8; ++nt) acc[nt] = (f32x4){0.f, 0.f, 0.f, 0.f};
            #pragma unroll
            for (int nt = 0; nt < 8; ++nt) {
                const int feat = nt * 16 + lr;
                #pragma unroll
                for (int ks = 0; ks < 2; ++ks) {
                    const int off = feat * 64 + ((((ks * 4 + lq) ^ (feat & 7))) << 3);
                    f16x8 bh = *(const f16x8*)&sWh[0][off];
                    f16x8 bl = *(const f16x8*)&sWh[1][off];
                    acc[nt] = __builtin_amdgcn_mfma_f32_16x16x32_f16(ap[ks], bh, acc[nt], 0, 0, 0);
                    acc[nt] = __builtin_amdgcn_mfma_f32_16x16x32_f16(ap[ks], bl, acc[nt], 0, 0, 0);
                }
            }
            float invr[4];
            #pragma unroll
            for (int r = 0; r < 4; ++r) invr[r] = __shfl(inv, lq * 4 + r, 64);

            if (L == 0) {
                __syncthreads();   // all WhT reads done -> overwrite with h1
                #pragma unroll
                for (int nt = 0; nt < 8; ++nt) {
                    const int feat = nt * 16 + lr;
                    #pragma unroll
                    for (int r = 0; r < 4; ++r) {
                        const int node = wave * 16 + lq * 4 + r;
                        const float v = elu1(acc[nt][r] * invr[r]);
                        const f16 hi = (f16)v;
                        const int off = idxH(node, feat);
                        sWh[0][off] = hi;
                        sWh[1][off] = (f16)(v - (float)hi);
                    }
                }
                // visibility barrier = first barrier of Phase F
            } else {
                // pooling from registers: pooled[feat] = elu(max_node h2pre)
                #pragma unroll
                for (int nt = 0; nt < 8; ++nt) {
                    float mx = -1e30f;
                    #pragma unroll
                    for (int r = 0; r < 4; ++r) mx = fmaxf(mx, acc[nt][r] * invr[r]);
                    mx = fmaxf(mx, __shfl_xor(mx, 16, 64));
                    mx = fmaxf(mx, __shfl_xor(mx, 32, 64));
                    if (lq == 0) sPoolW[wave][nt * 16 + lr] = mx;
                }
                __syncthreads();
                if (t < 128)
                    sPool[t] = elu1(fmaxf(fmaxf(sPoolW[0][t], sPoolW[1][t]),
                                          fmaxf(sPoolW[2][t], sPoolW[3][t])));
                __syncthreads();
            }
        }
    }

    // ---- Readout MLP (fp32, parallelized) ----
    {
        float* part = &sPoolW[0][0];    // reuse as [8][32]
        const int o = t & 31, c = t >> 5;
        float s = 0.f;
        #pragma unroll
        for (int kk = 0; kk < 16; ++kk)
            s = fmaf(sPool[c * 16 + kk], mw1[(c * 16 + kk) * 32 + o], s);
        part[c * 32 + o] = s;
    }
    __syncthreads();
    if (t < 32) {
        const float* part = &sPoolW[0][0];
        float s = mb1[t];
        #pragma unroll
        for (int c = 0; c < 8; ++c) s += part[c * 32 + t];
        sHid[t] = fmaxf(s, 0.0f);
    }
    __syncthreads();
    if (t < 128) {
        float s = mb2[t];
        #pragma unroll 8
        for (int q = 0; q < 32; ++q) s = fmaf(sHid[q], mw2[q * 128 + t], s);
        sRaw[t] = fmaxf(s, 0.0f) + 1e-6f;
    }
    __syncthreads();
    if (t < 128) {
        float v = sRaw[t];
        #pragma unroll
        for (int off = 32; off > 0; off >>= 1) v += __shfl_down(v, off, 64);
        if ((t & 63) == 0) sSums[t >> 6] = v;
    }
    __syncthreads();
    if (t < 64) {
        const float sumD = sSums[0] + 1e-6f;
        const float sumP = sSums[1] + 1e-6f;
        out[b * 64 + t] = sRaw[64 + t] / sumP;                     // power  (PMAX = 1)
        out[NBATCH * 64 + b * 64 + t] = 98.425f * sRaw[t] / sumD;  // delta  (Bmax = 98.425)
    }
}

extern "C" void kernel_launch(void* const* d_in, const int* in_sizes, int n_in,
                              void* d_out, int out_size, void* d_ws, size_t ws_size,
                              hipStream_t stream) {
    const float* users = (const float*)d_in[0];
    const float* W1    = (const float*)d_in[1];
    const float* a1    = (const float*)d_in[2];
    const float* W2    = (const float*)d_in[3];
    const float* a2    = (const float*)d_in[4];
    const float* mw1   = (const float*)d_in[5];
    const float* mb1   = (const float*)d_in[6];
    const float* mw2   = (const float*)d_in[7];
    const float* mb2   = (const float*)d_in[8];
    float* out = (float*)d_out;
    f16* w2t = (f16*)d_ws;

    w2t_prep<<<64, 256, 0, stream>>>(W2, w2t);
    gat_kernel<<<NBATCH, 256, 0, stream>>>(users, W1, a1, a2, w2t,
                                           mw1, mb1, mw2, mb2, out);
}

// Round 5
// 189.684 us; speedup vs baseline: 1.2902x; 1.2902x over previous
//
#include <hip/hip_runtime.h>

#define NBATCH 4096

typedef _Float16 f16;
typedef __attribute__((ext_vector_type(8))) _Float16 f16x8;
typedef __attribute__((ext_vector_type(4))) _Float16 f16x4;
typedef __attribute__((ext_vector_type(2))) _Float16 f16x2;
typedef __attribute__((ext_vector_type(4))) float f32x4;

__device__ __forceinline__ float lrelu(float x) { return x > 0.0f ? x : 0.2f * x; }
__device__ __forceinline__ float elu1(float x)  { return x > 0.0f ? x : __expf(x) - 1.0f; }

// W2 (128x128 f32 row-major) -> W2^T f16: w2t[n][k] = W2[k][n]
__global__ void w2t_prep(const float* __restrict__ W2, f16* __restrict__ w2t) {
    int idx = blockIdx.x * 256 + threadIdx.x;     // 16384
    int k = idx >> 7, n = idx & 127;              // coalesced read
    w2t[n * 128 + k] = (f16)W2[k * 128 + n];
}

// LDS layouts (XOR-swizzled, every 16B group aligned):
//   WhT[feat][node] 128x64 : off = f*64 + (((n>>3)^(f&7))<<3) + (n&7)
//   h1 [node][feat] 64x128 : off = n*128 + (((f>>3)^(n&15))<<3) + (f&7)
__device__ __forceinline__ int idxWh(int f, int n) { return f * 64  + ((((n >> 3) ^ (f & 7)))  << 3) + (n & 7); }
__device__ __forceinline__ int idxH (int n, int f) { return n * 128 + ((((f >> 3) ^ (n & 15))) << 3) + (f & 7); }

__global__ __launch_bounds__(256)   // NO min-waves clause: R4's (256,4) capped unified VGPR+AGPR
                                    // at 128 -> 64 arch VGPRs -> 278 MB scratch spills (the R4 regression)
void gat_kernel(const float* __restrict__ users,
                const float* __restrict__ W1,
                const float* __restrict__ a1,
                const float* __restrict__ a2,
                const f16* __restrict__ w2t,
                const float* __restrict__ mw1,
                const float* __restrict__ mb1,
                const float* __restrict__ mw2,
                const float* __restrict__ mb2,
                float* __restrict__ out)
{
    const int b = blockIdx.x;
    const int t = threadIdx.x;
    const int wave = t >> 6;
    const int lane = t & 63;
    const int lr = lane & 15;
    const int lq = lane >> 4;

    __shared__ f16 sWh[2][8192];      // hi/lo planes: Wh1T -> h1 -> Wh2T  (32 KB)
    __shared__ float sSi[64], sSj[64];
    __shared__ float sPoolW[4][128];  // pooling partials; reused as readout partials [8][32]
    __shared__ float sPool[128];
    __shared__ float sHid[32];
    __shared__ float sRaw[128];
    __shared__ float sSums[2];

    // ---- Phase B: Wh1 = users @ W1 (hi/lo into WhT) + fp32 scores si/sj fused ----
    {
        const int a = t >> 3;          // node pair (2a, 2a+1); 8 threads per pair
        const int fl = t & 7;          // f = fl + 8k  -> f&7 varies across lanes (bank spread)
        const int n0 = 2 * a;
        const float* ub = users + b * 192 + n0 * 3;
        float2 u01 = *(const float2*)(ub);
        float2 u23 = *(const float2*)(ub + 2);
        float2 u45 = *(const float2*)(ub + 4);
        const float x0 = u01.x, y0 = u01.y, z0 = u23.x;
        const float x1 = u23.y, y1 = u45.x, z1 = u45.y;
        float si0 = 0.f, sj0 = 0.f, si1 = 0.f, sj1 = 0.f;
        #pragma unroll
        for (int k = 0; k < 16; ++k) {
            const int f = fl + 8 * k;
            const float w0 = W1[f], w1 = W1[128 + f], w2 = W1[256 + f];
            const float v0 = fmaf(x0, w0, fmaf(y0, w1, z0 * w2));
            const float v1 = fmaf(x1, w0, fmaf(y1, w1, z1 * w2));
            si0 = fmaf(v0, a1[f], si0);       sj0 = fmaf(v0, a1[128 + f], sj0);
            si1 = fmaf(v1, a1[f], si1);       sj1 = fmaf(v1, a1[128 + f], sj1);
            const f16 h0 = (f16)v0, h1v = (f16)v1;
            const f16 l0 = (f16)(v0 - (float)h0), l1 = (f16)(v1 - (float)h1v);
            const int off = idxWh(f, n0);     // n0 even -> pair contiguous in same 8-group
            *(f16x2*)&sWh[0][off] = (f16x2){h0, h1v};
            *(f16x2*)&sWh[1][off] = (f16x2){l0, l1};
        }
        #pragma unroll
        for (int m = 1; m < 8; m <<= 1) {
            si0 += __shfl_xor(si0, m, 64);  sj0 += __shfl_xor(sj0, m, 64);
            si1 += __shfl_xor(si1, m, 64);  sj1 += __shfl_xor(sj1, m, 64);
        }
        if (fl == 0) {
            sSi[n0] = si0; sSi[n0 + 1] = si1;
            sSj[n0] = sj0; sSj[n0 + 1] = sj1;
        }
    }
    __syncthreads();

    for (int L = 0; L < 2; ++L) {
        if (L == 1) {
            // ---- Phase F: Wh2 = h1 @ W2 (A = h1 hi/lo LDS, B = w2t global/L1) ----
            __syncthreads();   // h1 stores visible
            const int row = wave * 16 + lr;
            f16x8 ahi[4], alo[4];
            #pragma unroll
            for (int ks = 0; ks < 4; ++ks) {
                const int off = row * 128 + ((((ks * 4 + lq) ^ (row & 15))) << 3);
                ahi[ks] = *(const f16x8*)&sWh[0][off];
                alo[ks] = *(const f16x8*)&sWh[1][off];
            }
            __syncthreads();   // all h1 reads done -> sWh free for Wh2T stores

            f32x4 acc[8];
            #pragma unroll
            for (int nt = 0; nt < 8; ++nt) acc[nt] = (f32x4){0.f, 0.f, 0.f, 0.f};
            #pragma unroll
            for (int nt = 0; nt < 8; ++nt) {
                const f16* bp = w2t + (nt * 16 + lr) * 128 + lq * 8;
                #pragma unroll
                for (int ks = 0; ks < 4; ++ks) {
                    f16x8 bf = *(const f16x8*)(bp + ks * 32);
                    acc[nt] = __builtin_amdgcn_mfma_f32_16x16x32_f16(ahi[ks], bf, acc[nt], 0, 0, 0);
                    acc[nt] = __builtin_amdgcn_mfma_f32_16x16x32_f16(alo[ks], bf, acc[nt], 0, 0, 0);
                }
            }
            // fp32 scores from accumulators: si/sj for nodes wave*16+lq*4+r
            // (a2 loads AFTER the MFMA loop -> short live range, no spill pressure)
            float sir[4] = {0.f, 0.f, 0.f, 0.f}, sjr[4] = {0.f, 0.f, 0.f, 0.f};
            #pragma unroll
            for (int nt = 0; nt < 8; ++nt) {
                const float a2f = a2[nt * 16 + lr];
                const float a2s = a2[128 + nt * 16 + lr];
                #pragma unroll
                for (int r = 0; r < 4; ++r) {
                    sir[r] = fmaf(acc[nt][r], a2f, sir[r]);
                    sjr[r] = fmaf(acc[nt][r], a2s, sjr[r]);
                }
            }
            #pragma unroll
            for (int m = 1; m < 16; m <<= 1) {
                #pragma unroll
                for (int r = 0; r < 4; ++r) {
                    sir[r] += __shfl_xor(sir[r], m, 64);
                    sjr[r] += __shfl_xor(sjr[r], m, 64);
                }
            }
            // store Wh2T hi/lo (D: row=node=wave*16+lq*4+r, col=feat=nt*16+lr)
            #pragma unroll
            for (int nt = 0; nt < 8; ++nt) {
                const int feat = nt * 16 + lr;
                const int g = wave * 2 + (lq >> 1);
                const int base = feat * 64 + (((g ^ (feat & 7))) << 3) + ((lq & 1) * 4);
                f16x4 hv, lv;
                #pragma unroll
                for (int r = 0; r < 4; ++r) {
                    const float v = acc[nt][r];
                    const f16 hi = (f16)v;
                    hv[r] = hi;
                    lv[r] = (f16)(v - (float)hi);
                }
                *(f16x4*)&sWh[0][base] = hv;
                *(f16x4*)&sWh[1][base] = lv;
            }
            if (lr == 0) {
                #pragma unroll
                for (int r = 0; r < 4; ++r) {
                    const int n = wave * 16 + lq * 4 + r;
                    sSi[n] = sir[r];
                    sSj[n] = sjr[r];
                }
            }
            __syncthreads();
        }

        // ---- Phase E (fused softmax): h = elu(diag(inv) * P @ Wh) ----
        {
            const int row = wave * 16 + lr;          // A-fragment row
            const float si = sSi[row];
            float sjv[16];
            #pragma unroll
            for (int x = 0; x < 16; ++x)
                sjv[x] = sSj[(x >> 3) * 32 + lq * 8 + (x & 7)];
            float mj = sjv[0];
            #pragma unroll
            for (int x = 1; x < 16; ++x) mj = fmaxf(mj, sjv[x]);
            mj = fmaxf(mj, __shfl_xor(mj, 16, 64));
            mj = fmaxf(mj, __shfl_xor(mj, 32, 64));
            const float mi = lrelu(si + mj);         // lrelu monotone -> row max

            f16x8 ap[2];
            float lsum = 0.f;
            #pragma unroll
            for (int ks = 0; ks < 2; ++ks) {
                #pragma unroll
                for (int jj = 0; jj < 8; ++jj) {
                    const float p = __expf(lrelu(si + sjv[ks * 8 + jj]) - mi);
                    const f16 ph = (f16)p;
                    lsum += (float)ph;               // debiased denominator
                    ap[ks][jj] = ph;
                }
            }
            lsum += __shfl_xor(lsum, 16, 64);
            lsum += __shfl_xor(lsum, 32, 64);
            const float inv = 1.0f / lsum;

            f32x4 acc[8];
            #pragma unroll
            for (int nt = 0; nt < 8; ++nt) acc[nt] = (f32x4){0.f, 0.f, 0.f, 0.f};
            #pragma unroll
            for (int nt = 0; nt < 8; ++nt) {
                const int feat = nt * 16 + lr;
                #pragma unroll
                for (int ks = 0; ks < 2; ++ks) {
                    const int off = feat * 64 + ((((ks * 4 + lq) ^ (feat & 7))) << 3);
                    f16x8 bh = *(const f16x8*)&sWh[0][off];
                    f16x8 bl = *(const f16x8*)&sWh[1][off];
                    acc[nt] = __builtin_amdgcn_mfma_f32_16x16x32_f16(ap[ks], bh, acc[nt], 0, 0, 0);
                    acc[nt] = __builtin_amdgcn_mfma_f32_16x16x32_f16(ap[ks], bl, acc[nt], 0, 0, 0);
                }
            }
            float invr[4];
            #pragma unroll
            for (int r = 0; r < 4; ++r) invr[r] = __shfl(inv, lq * 4 + r, 64);

            if (L == 0) {
                __syncthreads();   // all WhT reads done -> overwrite with h1
                #pragma unroll
                for (int nt = 0; nt < 8; ++nt) {
                    const int feat = nt * 16 + lr;
                    #pragma unroll
                    for (int r = 0; r < 4; ++r) {
                        const int node = wave * 16 + lq * 4 + r;
                        const float v = elu1(acc[nt][r] * invr[r]);
                        const f16 hi = (f16)v;
                        const int off = idxH(node, feat);
                        sWh[0][off] = hi;
                        sWh[1][off] = (f16)(v - (float)hi);
                    }
                }
                // visibility barrier = first barrier of Phase F
            } else {
                // pooling from registers: pooled[feat] = elu(max_node h2pre)
                #pragma unroll
                for (int nt = 0; nt < 8; ++nt) {
                    float mx = -1e30f;
                    #pragma unroll
                    for (int r = 0; r < 4; ++r) mx = fmaxf(mx, acc[nt][r] * invr[r]);
                    mx = fmaxf(mx, __shfl_xor(mx, 16, 64));
                    mx = fmaxf(mx, __shfl_xor(mx, 32, 64));
                    if (lq == 0) sPoolW[wave][nt * 16 + lr] = mx;
                }
                __syncthreads();
                if (t < 128)
                    sPool[t] = elu1(fmaxf(fmaxf(sPoolW[0][t], sPoolW[1][t]),
                                          fmaxf(sPoolW[2][t], sPoolW[3][t])));
                __syncthreads();
            }
        }
    }

    // ---- Readout MLP (fp32, parallelized) ----
    {
        float* part = &sPoolW[0][0];    // reuse as [8][32]
        const int o = t & 31, c = t >> 5;
        float s = 0.f;
        #pragma unroll
        for (int kk = 0; kk < 16; ++kk)
            s = fmaf(sPool[c * 16 + kk], mw1[(c * 16 + kk) * 32 + o], s);
        part[c * 32 + o] = s;
    }
    __syncthreads();
    if (t < 32) {
        const float* part = &sPoolW[0][0];
        float s = mb1[t];
        #pragma unroll
        for (int c = 0; c < 8; ++c) s += part[c * 32 + t];
        sHid[t] = fmaxf(s, 0.0f);
    }
    __syncthreads();
    if (t < 128) {
        float s = mb2[t];
        #pragma unroll 8
        for (int q = 0; q < 32; ++q) s = fmaf(sHid[q], mw2[q * 128 + t], s);
        sRaw[t] = fmaxf(s, 0.0f) + 1e-6f;
    }
    __syncthreads();
    if (t < 128) {
        float v = sRaw[t];
        #pragma unroll
        for (int off = 32; off > 0; off >>= 1) v += __shfl_down(v, off, 64);
        if ((t & 63) == 0) sSums[t >> 6] = v;
    }
    __syncthreads();
    if (t < 64) {
        const float sumD = sSums[0] + 1e-6f;
        const float sumP = sSums[1] + 1e-6f;
        out[b * 64 + t] = sRaw[64 + t] / sumP;                     // power  (PMAX = 1)
        out[NBATCH * 64 + b * 64 + t] = 98.425f * sRaw[t] / sumD;  // delta  (Bmax = 98.425)
    }
}

extern "C" void kernel_launch(void* const* d_in, const int* in_sizes, int n_in,
                              void* d_out, int out_size, void* d_ws, size_t ws_size,
                              hipStream_t stream) {
    const float* users = (const float*)d_in[0];
    const float* W1    = (const float*)d_in[1];
    const float* a1    = (const float*)d_in[2];
    const float* W2    = (const float*)d_in[3];
    const float* a2    = (const float*)d_in[4];
    const float* mw1   = (const float*)d_in[5];
    const float* mb1   = (const float*)d_in[6];
    const float* mw2   = (const float*)d_in[7];
    const float* mb2   = (const float*)d_in[8];
    float* out = (float*)d_out;
    f16* w2t = (f16*)d_ws;

    w2t_prep<<<64, 256, 0, stream>>>(W2, w2t);
    gat_kernel<<<NBATCH, 256, 0, stream>>>(users, W1, a1, a2, w2t,
                                           mw1, mb1, mw2, mb2, out);
}

// Round 6
// 187.708 us; speedup vs baseline: 1.3038x; 1.0105x over previous
//
#include <hip/hip_runtime.h>

#define NBATCH 4096

typedef _Float16 f16;
typedef __attribute__((ext_vector_type(8))) _Float16 f16x8;
typedef __attribute__((ext_vector_type(4))) _Float16 f16x4;
typedef __attribute__((ext_vector_type(2))) _Float16 f16x2;
typedef __attribute__((ext_vector_type(4))) float f32x4;

__device__ __forceinline__ float lrelu(float x) { return x > 0.0f ? x : 0.2f * x; }
__device__ __forceinline__ float elu1(float x)  { return x > 0.0f ? x : __expf(x) - 1.0f; }

// W2 (128x128 f32 row-major) -> W2^T f16: w2t[n][k] = W2[k][n]
__global__ void w2t_prep(const float* __restrict__ W2, f16* __restrict__ w2t) {
    int idx = blockIdx.x * 256 + threadIdx.x;     // 16384
    int k = idx >> 7, n = idx & 127;              // coalesced read
    w2t[n * 128 + k] = (f16)W2[k * 128 + n];
}

// LDS layouts (XOR-swizzled, every 16B group aligned):
//   WhT[feat][node] 128x64 : off = f*64 + (((n>>3)^(f&7))<<3) + (n&7)
//   h1 [node][feat] 64x128 : off = n*128 + (((f>>3)^(n&15))<<3) + (f&7)
__device__ __forceinline__ int idxWh(int f, int n) { return f * 64  + ((((n >> 3) ^ (f & 7)))  << 3) + (n & 7); }
__device__ __forceinline__ int idxH (int n, int f) { return n * 128 + ((((f >> 3) ^ (n & 15))) << 3) + (f & 7); }

__global__ __launch_bounds__(256)   // no min-waves clause (R4: (256,4) -> 64 VGPR -> 278 MB spills)
void gat_kernel(const float* __restrict__ users,
                const float* __restrict__ W1,
                const float* __restrict__ a1,
                const float* __restrict__ a2,
                const f16* __restrict__ w2t,
                const float* __restrict__ mw1,
                const float* __restrict__ mb1,
                const float* __restrict__ mw2,
                const float* __restrict__ mb2,
                float* __restrict__ out)
{
    const int b = blockIdx.x;
    const int t = threadIdx.x;
    const int wave = t >> 6;
    const int lane = t & 63;
    const int lr = lane & 15;
    const int lq = lane >> 4;

    __shared__ f16 sWh[8192];         // single f16 plane: Wh1T -> h1 -> Wh2T  (16 KB)
    __shared__ float sSi[64], sSj[64];
    __shared__ float sPoolW[4][128];  // pooling partials; reused as readout partials [8][32]
    __shared__ float sPool[128];
    __shared__ float sHid[32];
    __shared__ float sRaw[128];
    __shared__ float sSums[2];

    // ---- Phase B: Wh1 = users @ W1 (f16 into WhT) + fp32 scores si/sj fused ----
    {
        const int a = t >> 3;          // node pair (2a, 2a+1); 8 threads per pair
        const int fl = t & 7;          // f = fl + 8k  -> f&7 varies across lanes (bank spread)
        const int n0 = 2 * a;
        const float* ub = users + b * 192 + n0 * 3;
        float2 u01 = *(const float2*)(ub);
        float2 u23 = *(const float2*)(ub + 2);
        float2 u45 = *(const float2*)(ub + 4);
        const float x0 = u01.x, y0 = u01.y, z0 = u23.x;
        const float x1 = u23.y, y1 = u45.x, z1 = u45.y;
        float si0 = 0.f, sj0 = 0.f, si1 = 0.f, sj1 = 0.f;
        #pragma unroll
        for (int k = 0; k < 16; ++k) {
            const int f = fl + 8 * k;
            const float w0 = W1[f], w1 = W1[128 + f], w2 = W1[256 + f];
            const float v0 = fmaf(x0, w0, fmaf(y0, w1, z0 * w2));
            const float v1 = fmaf(x1, w0, fmaf(y1, w1, z1 * w2));
            si0 = fmaf(v0, a1[f], si0);       sj0 = fmaf(v0, a1[128 + f], sj0);
            si1 = fmaf(v1, a1[f], si1);       sj1 = fmaf(v1, a1[128 + f], sj1);
            *(f16x2*)&sWh[idxWh(f, n0)] = (f16x2){(f16)v0, (f16)v1};
        }
        #pragma unroll
        for (int m = 1; m < 8; m <<= 1) {
            si0 += __shfl_xor(si0, m, 64);  sj0 += __shfl_xor(sj0, m, 64);
            si1 += __shfl_xor(si1, m, 64);  sj1 += __shfl_xor(sj1, m, 64);
        }
        if (fl == 0) {
            sSi[n0] = si0; sSi[n0 + 1] = si1;
            sSj[n0] = sj0; sSj[n0 + 1] = sj1;
        }
    }
    __syncthreads();

    for (int L = 0; L < 2; ++L) {
        if (L == 1) {
            // ---- Phase F: Wh2 = h1 @ W2 (A = h1 f16 LDS, B = w2t global/L1) ----
            __syncthreads();   // h1 stores visible
            const int row = wave * 16 + lr;
            f16x8 ahi[4];
            #pragma unroll
            for (int ks = 0; ks < 4; ++ks) {
                const int off = row * 128 + ((((ks * 4 + lq) ^ (row & 15))) << 3);
                ahi[ks] = *(const f16x8*)&sWh[off];
            }
            __syncthreads();   // all h1 reads done -> sWh free for Wh2T stores

            f32x4 acc[8];
            #pragma unroll
            for (int nt = 0; nt < 8; ++nt) acc[nt] = (f32x4){0.f, 0.f, 0.f, 0.f};
            #pragma unroll
            for (int nt = 0; nt < 8; ++nt) {
                const f16* bp = w2t + (nt * 16 + lr) * 128 + lq * 8;
                #pragma unroll
                for (int ks = 0; ks < 4; ++ks) {
                    f16x8 bf = *(const f16x8*)(bp + ks * 32);
                    acc[nt] = __builtin_amdgcn_mfma_f32_16x16x32_f16(ahi[ks], bf, acc[nt], 0, 0, 0);
                }
            }
            // fp32 scores from accumulators: si/sj for nodes wave*16+lq*4+r
            float sir[4] = {0.f, 0.f, 0.f, 0.f}, sjr[4] = {0.f, 0.f, 0.f, 0.f};
            #pragma unroll
            for (int nt = 0; nt < 8; ++nt) {
                const float a2f = a2[nt * 16 + lr];
                const float a2s = a2[128 + nt * 16 + lr];
                #pragma unroll
                for (int r = 0; r < 4; ++r) {
                    sir[r] = fmaf(acc[nt][r], a2f, sir[r]);
                    sjr[r] = fmaf(acc[nt][r], a2s, sjr[r]);
                }
            }
            #pragma unroll
            for (int m = 1; m < 16; m <<= 1) {
                #pragma unroll
                for (int r = 0; r < 4; ++r) {
                    sir[r] += __shfl_xor(sir[r], m, 64);
                    sjr[r] += __shfl_xor(sjr[r], m, 64);
                }
            }
            // store Wh2T f16 (D: row=node=wave*16+lq*4+r, col=feat=nt*16+lr)
            #pragma unroll
            for (int nt = 0; nt < 8; ++nt) {
                const int feat = nt * 16 + lr;
                const int g = wave * 2 + (lq >> 1);
                const int base = feat * 64 + (((g ^ (feat & 7))) << 3) + ((lq & 1) * 4);
                f16x4 hv;
                #pragma unroll
                for (int r = 0; r < 4; ++r) hv[r] = (f16)acc[nt][r];
                *(f16x4*)&sWh[base] = hv;
            }
            if (lr == 0) {
                #pragma unroll
                for (int r = 0; r < 4; ++r) {
                    const int n = wave * 16 + lq * 4 + r;
                    sSi[n] = sir[r];
                    sSj[n] = sjr[r];
                }
            }
            __syncthreads();
        }

        // ---- Phase E (fused softmax): h = elu(diag(inv) * P @ Wh) ----
        {
            const int row = wave * 16 + lr;          // A-fragment row
            const float si = sSi[row];
            float sjv[16];
            #pragma unroll
            for (int x = 0; x < 16; ++x)
                sjv[x] = sSj[(x >> 3) * 32 + lq * 8 + (x & 7)];
            float mj = sjv[0];
            #pragma unroll
            for (int x = 1; x < 16; ++x) mj = fmaxf(mj, sjv[x]);
            mj = fmaxf(mj, __shfl_xor(mj, 16, 64));
            mj = fmaxf(mj, __shfl_xor(mj, 32, 64));
            const float mi = lrelu(si + mj);         // lrelu monotone -> row max

            f16x8 ap[2];
            float lsum = 0.f;
            #pragma unroll
            for (int ks = 0; ks < 2; ++ks) {
                #pragma unroll
                for (int jj = 0; jj < 8; ++jj) {
                    const float p = __expf(lrelu(si + sjv[ks * 8 + jj]) - mi);
                    const f16 ph = (f16)p;
                    lsum += (float)ph;               // debiased denominator
                    ap[ks][jj] = ph;
                }
            }
            lsum += __shfl_xor(lsum, 16, 64);
            lsum += __shfl_xor(lsum, 32, 64);
            const float inv = 1.0f / lsum;

            f32x4 acc[8];
            #pragma unroll
            for (int nt = 0; nt < 8; ++nt) acc[nt] = (f32x4){0.f, 0.f, 0.f, 0.f};
            #pragma unroll
            for (int nt = 0; nt < 8; ++nt) {
                const int feat = nt * 16 + lr;
                #pragma unroll
                for (int ks = 0; ks < 2; ++ks) {
                    const int off = feat * 64 + ((((ks * 4 + lq) ^ (feat & 7))) << 3);
                    f16x8 bh = *(const f16x8*)&sWh[off];
                    acc[nt] = __builtin_amdgcn_mfma_f32_16x16x32_f16(ap[ks], bh, acc[nt], 0, 0, 0);
                }
            }
            float invr[4];
            #pragma unroll
            for (int r = 0; r < 4; ++r) invr[r] = __shfl(inv, lq * 4 + r, 64);

            if (L == 0) {
                __syncthreads();   // all WhT reads done -> overwrite with h1
                #pragma unroll
                for (int nt = 0; nt < 8; ++nt) {
                    const int feat = nt * 16 + lr;
                    #pragma unroll
                    for (int r = 0; r < 4; ++r) {
                        const int node = wave * 16 + lq * 4 + r;
                        const float v = elu1(acc[nt][r] * invr[r]);
                        sWh[idxH(node, feat)] = (f16)v;
                    }
                }
                // visibility barrier = first barrier of Phase F
            } else {
                // pooling from registers: pooled[feat] = elu(max_node h2pre)
                #pragma unroll
                for (int nt = 0; nt < 8; ++nt) {
                    float mx = -1e30f;
                    #pragma unroll
                    for (int r = 0; r < 4; ++r) mx = fmaxf(mx, acc[nt][r] * invr[r]);
                    mx = fmaxf(mx, __shfl_xor(mx, 16, 64));
                    mx = fmaxf(mx, __shfl_xor(mx, 32, 64));
                    if (lq == 0) sPoolW[wave][nt * 16 + lr] = mx;
                }
                __syncthreads();
                if (t < 128)
                    sPool[t] = elu1(fmaxf(fmaxf(sPoolW[0][t], sPoolW[1][t]),
                                          fmaxf(sPoolW[2][t], sPoolW[3][t])));
                __syncthreads();
            }
        }
    }

    // ---- Readout MLP (fp32, parallelized) ----
    {
        float* part = &sPoolW[0][0];    // reuse as [8][32]
        const int o = t & 31, c = t >> 5;
        float s = 0.f;
        #pragma unroll
        for (int kk = 0; kk < 16; ++kk)
            s = fmaf(sPool[c * 16 + kk], mw1[(c * 16 + kk) * 32 + o], s);
        part[c * 32 + o] = s;
    }
    __syncthreads();
    if (t < 32) {
        const float* part = &sPoolW[0][0];
        float s = mb1[t];
        #pragma unroll
        for (int c = 0; c < 8; ++c) s += part[c * 32 + t];
        sHid[t] = fmaxf(s, 0.0f);
    }
    __syncthreads();
    if (t < 128) {
        float s = mb2[t];
        #pragma unroll 8
        for (int q = 0; q < 32; ++q) s = fmaf(sHid[q], mw2[q * 128 + t], s);
        sRaw[t] = fmaxf(s, 0.0f) + 1e-6f;
    }
    __syncthreads();
    if (t < 128) {
        float v = sRaw[t];
        #pragma unroll
        for (int off = 32; off > 0; off >>= 1) v += __shfl_down(v, off, 64);
        if ((t & 63) == 0) sSums[t >> 6] = v;
    }
    __syncthreads();
    if (t < 64) {
        const float sumD = sSums[0] + 1e-6f;
        const float sumP = sSums[1] + 1e-6f;
        out[b * 64 + t] = sRaw[64 + t] / sumP;                     // power  (PMAX = 1)
        out[NBATCH * 64 + b * 64 + t] = 98.425f * sRaw[t] / sumD;  // delta  (Bmax = 98.425)
    }
}

extern "C" void kernel_launch(void* const* d_in, const int* in_sizes, int n_in,
                              void* d_out, int out_size, void* d_ws, size_t ws_size,
                              hipStream_t stream) {
    const float* users = (const float*)d_in[0];
    const float* W1    = (const float*)d_in[1];
    const float* a1    = (const float*)d_in[2];
    const float* W2    = (const float*)d_in[3];
    const float* a2    = (const float*)d_in[4];
    const float* mw1   = (const float*)d_in[5];
    const float* mb1   = (const float*)d_in[6];
    const float* mw2   = (const float*)d_in[7];
    const float* mb2   = (const float*)d_in[8];
    float* out = (float*)d_out;
    f16* w2t = (f16*)d_ws;

    w2t_prep<<<64, 256, 0, stream>>>(W2, w2t);
    gat_kernel<<<NBATCH, 256, 0, stream>>>(users, W1, a1, a2, w2t,
                                           mw1, mb1, mw2, mb2, out);
}

// Round 7
// 143.035 us; speedup vs baseline: 1.7110x; 1.3123x over previous
//
#include <hip/hip_runtime.h>

#define NBATCH 4096
#define OUT2 (NBATCH * 64)

typedef _Float16 f16;
typedef __attribute__((ext_vector_type(8))) _Float16 f16x8;
typedef __attribute__((ext_vector_type(4))) _Float16 f16x4;
typedef __attribute__((ext_vector_type(4))) float f32x4;

__device__ __forceinline__ float lrelu(float x) { return x > 0.0f ? x : 0.2f * x; }
__device__ __forceinline__ float elu1(float x)  { return x > 0.0f ? x : __expf(x) - 1.0f; }

// W2 (128x128 f32 row-major) -> W2^T f16: w2t[n][k] = W2[k][n]
__global__ void w2t_prep(const float* __restrict__ W2, f16* __restrict__ w2t) {
    int idx = blockIdx.x * 256 + threadIdx.x;
    int k = idx >> 7, n = idx & 127;
    w2t[n * 128 + k] = (f16)W2[k * 128 + n];
}

// sMain layout (feat-major, XOR-swizzled, 16B groups aligned):
//   WhT[f][n] at f*64 + (((n>>3)^(f&7))<<3) + (n&7)     (Wh1T, then Wh2T in place)
// sBounce (one 16-node h1 slab, node-major): [nl][f] at nl*128 + ((((f>>3)^nl)&15)<<3) + (f&7)

__global__ __launch_bounds__(64)
void gat_kernel(const float* __restrict__ users,
                const float* __restrict__ W1,
                const float* __restrict__ a1,
                const float* __restrict__ a2,
                const f16* __restrict__ w2t,
                const float* __restrict__ mw1,
                const float* __restrict__ mb1,
                const float* __restrict__ mw2,
                const float* __restrict__ mb2,
                float* __restrict__ out)
{
    const int b = blockIdx.x;
    const int lane = threadIdx.x;   // one wave per block, one batch per wave
    const int lr = lane & 15;
    const int lq = lane >> 4;

    __shared__ f16  sMain[8192];     // 16 KB: Wh1T -> Wh2T (in place)
    __shared__ f16  sBounce[2048];   // 4 KB: one 16-node h1 slab
    __shared__ float sSi[64], sSj[64];
    __shared__ float sPool[128];
    __shared__ float sHid[32];

    // ================= Phase B': Wh1 = users @ W1 via MFMA (K=3 zero-padded) ======
    {
        f16x8 bw[8];
        #pragma unroll
        for (int nt = 0; nt < 8; ++nt) {
            #pragma unroll
            for (int j = 0; j < 8; ++j) bw[nt][j] = (f16)0.f;
            if (lq == 0) {
                #pragma unroll
                for (int j = 0; j < 3; ++j)
                    bw[nt][j] = (f16)W1[j * 128 + nt * 16 + lr];
            }
        }
        #pragma unroll
        for (int mt = 0; mt < 4; ++mt) {
            f16x8 af;
            #pragma unroll
            for (int j = 0; j < 8; ++j) af[j] = (f16)0.f;
            if (lq == 0) {
                const float* up = users + b * 192 + (mt * 16 + lr) * 3;
                af[0] = (f16)up[0]; af[1] = (f16)up[1]; af[2] = (f16)up[2];
            }
            f32x4 acc[8];
            #pragma unroll
            for (int nt = 0; nt < 8; ++nt) {
                acc[nt] = (f32x4){0.f, 0.f, 0.f, 0.f};
                acc[nt] = __builtin_amdgcn_mfma_f32_16x16x32_f16(af, bw[nt], acc[nt], 0, 0, 0);
            }
            // scores si/sj for rows mt*16+lq*4+r (fp32, from acc)
            float sir[4] = {0.f,0.f,0.f,0.f}, sjr[4] = {0.f,0.f,0.f,0.f};
            #pragma unroll
            for (int nt = 0; nt < 8; ++nt) {
                const float a1f = a1[nt * 16 + lr];
                const float a1s = a1[128 + nt * 16 + lr];
                #pragma unroll
                for (int r = 0; r < 4; ++r) {
                    sir[r] = fmaf(acc[nt][r], a1f, sir[r]);
                    sjr[r] = fmaf(acc[nt][r], a1s, sjr[r]);
                }
            }
            #pragma unroll
            for (int m = 1; m < 16; m <<= 1) {
                #pragma unroll
                for (int r = 0; r < 4; ++r) {
                    sir[r] += __shfl_xor(sir[r], m, 64);
                    sjr[r] += __shfl_xor(sjr[r], m, 64);
                }
            }
            if (lr == 0) {
                #pragma unroll
                for (int r = 0; r < 4; ++r) {
                    sSi[mt * 16 + lq * 4 + r] = sir[r];
                    sSj[mt * 16 + lq * 4 + r] = sjr[r];
                }
            }
            // store Wh1T (D row=node=mt*16+lq*4+r, col=feat=nt*16+lr)
            #pragma unroll
            for (int nt = 0; nt < 8; ++nt) {
                const int feat = nt * 16 + lr;
                const int g = mt * 2 + (lq >> 1);
                const int base = feat * 64 + ((g ^ (feat & 7)) << 3) + ((lq & 1) * 4);
                f16x4 hv;
                #pragma unroll
                for (int r = 0; r < 4; ++r) hv[r] = (f16)acc[nt][r];
                *(f16x4*)&sMain[base] = hv;
            }
        }
    }
    __syncthreads();   // single-wave: just a waitcnt

    // ================= Phase E0: h1 = elu(softmax(P) @ Wh1), h1 -> register frags ==
    f16x8 hf[4][4];    // the ENTIRE h1 as B-fragments: [node-tile][ks], 64 VGPRs
    {
        float sjv[16];
        #pragma unroll
        for (int x = 0; x < 16; ++x)
            sjv[x] = sSj[(x >> 3) * 32 + lq * 8 + (x & 7)];
        float mj = sjv[0];
        #pragma unroll
        for (int x = 1; x < 16; ++x) mj = fmaxf(mj, sjv[x]);
        mj = fmaxf(mj, __shfl_xor(mj, 16, 64));
        mj = fmaxf(mj, __shfl_xor(mj, 32, 64));

        #pragma unroll
        for (int mt = 0; mt < 4; ++mt) {
            const int row = mt * 16 + lr;
            const float si = sSi[row];
            const float mi = lrelu(si + mj);
            f16x8 ap0, ap1;
            float lsum = 0.f;
            #pragma unroll
            for (int jj = 0; jj < 8; ++jj) {
                float p = __expf(lrelu(si + sjv[jj]) - mi);
                f16 ph = (f16)p; lsum += (float)ph; ap0[jj] = ph;
                p = __expf(lrelu(si + sjv[8 + jj]) - mi);
                ph = (f16)p; lsum += (float)ph; ap1[jj] = ph;
            }
            lsum += __shfl_xor(lsum, 16, 64);
            lsum += __shfl_xor(lsum, 32, 64);
            const float inv = 1.0f / lsum;

            f32x4 acc[8];
            #pragma unroll
            for (int nt = 0; nt < 8; ++nt) {
                const int feat = nt * 16 + lr;
                f16x8 bh0 = *(const f16x8*)&sMain[feat * 64 + ((lq ^ (feat & 7)) << 3)];
                f16x8 bh1 = *(const f16x8*)&sMain[feat * 64 + (((4 + lq) ^ (feat & 7)) << 3)];
                acc[nt] = (f32x4){0.f, 0.f, 0.f, 0.f};
                acc[nt] = __builtin_amdgcn_mfma_f32_16x16x32_f16(ap0, bh0, acc[nt], 0, 0, 0);
                acc[nt] = __builtin_amdgcn_mfma_f32_16x16x32_f16(ap1, bh1, acc[nt], 0, 0, 0);
            }
            float invr[4];
            #pragma unroll
            for (int r = 0; r < 4; ++r) invr[r] = __shfl(inv, lq * 4 + r, 64);

            __syncthreads();   // previous mt's bounce reads done
            #pragma unroll
            for (int nt = 0; nt < 8; ++nt) {
                #pragma unroll
                for (int r = 0; r < 4; ++r) {
                    const float v = elu1(acc[nt][r] * invr[r]);
                    const int nl = lq * 4 + r;
                    const int f = nt * 16 + lr;
                    sBounce[nl * 128 + ((((f >> 3) ^ nl) & 15) << 3) + (f & 7)] = (f16)v;
                }
            }
            __syncthreads();
            #pragma unroll
            for (int ks = 0; ks < 4; ++ks)
                hf[mt][ks] = *(const f16x8*)&sBounce[lr * 128 + ((((lq + 4 * ks) ^ lr) & 15) << 3)];
        }
    }
    __syncthreads();   // all Wh1T reads done -> sMain free for Wh2T

    // ================= Phase F': Wh2T = W2T @ h1T (A = w2t global, B = hf regs) ====
    {
        float s2i[4] = {0.f,0.f,0.f,0.f}, s2j[4] = {0.f,0.f,0.f,0.f};
        #pragma unroll
        for (int f2t = 0; f2t < 8; ++f2t) {
            f16x8 aw[4];
            #pragma unroll
            for (int ks = 0; ks < 4; ++ks)
                aw[ks] = *(const f16x8*)(w2t + (f2t * 16 + lr) * 128 + lq * 8 + 32 * ks);
            f32x4 acc[4];
            #pragma unroll
            for (int ntile = 0; ntile < 4; ++ntile) {
                acc[ntile] = (f32x4){0.f, 0.f, 0.f, 0.f};
                #pragma unroll
                for (int ks = 0; ks < 4; ++ks)
                    acc[ntile] = __builtin_amdgcn_mfma_f32_16x16x32_f16(aw[ks], hf[ntile][ks], acc[ntile], 0, 0, 0);
            }
            // layer-2 scores: f2 = f2t*16 + lq*4 + r
            float a2f[4], a2s[4];
            #pragma unroll
            for (int r = 0; r < 4; ++r) {
                a2f[r] = a2[f2t * 16 + lq * 4 + r];
                a2s[r] = a2[128 + f2t * 16 + lq * 4 + r];
            }
            #pragma unroll
            for (int ntile = 0; ntile < 4; ++ntile) {
                #pragma unroll
                for (int r = 0; r < 4; ++r) {
                    s2i[ntile] = fmaf(acc[ntile][r], a2f[r], s2i[ntile]);
                    s2j[ntile] = fmaf(acc[ntile][r], a2s[r], s2j[ntile]);
                }
            }
            // store Wh2T rows f2 (scalar f16; D row=f2, col=node=ntile*16+lr)
            #pragma unroll
            for (int ntile = 0; ntile < 4; ++ntile) {
                const int n = ntile * 16 + lr;
                #pragma unroll
                for (int r = 0; r < 4; ++r) {
                    const int f2 = f2t * 16 + lq * 4 + r;
                    sMain[f2 * 64 + (((n >> 3) ^ (f2 & 7)) << 3) + (n & 7)] = (f16)acc[ntile][r];
                }
            }
        }
        #pragma unroll
        for (int ntile = 0; ntile < 4; ++ntile) {
            s2i[ntile] += __shfl_xor(s2i[ntile], 16, 64);
            s2i[ntile] += __shfl_xor(s2i[ntile], 32, 64);
            s2j[ntile] += __shfl_xor(s2j[ntile], 16, 64);
            s2j[ntile] += __shfl_xor(s2j[ntile], 32, 64);
        }
        if (lq == 0) {
            #pragma unroll
            for (int ntile = 0; ntile < 4; ++ntile) {
                sSi[ntile * 16 + lr] = s2i[ntile];
                sSj[ntile * 16 + lr] = s2j[ntile];
            }
        }
    }
    __syncthreads();

    // ================= Phase E1: h2 + max-pool (registers only) ====================
    {
        float sjv[16];
        #pragma unroll
        for (int x = 0; x < 16; ++x)
            sjv[x] = sSj[(x >> 3) * 32 + lq * 8 + (x & 7)];
        float mj = sjv[0];
        #pragma unroll
        for (int x = 1; x < 16; ++x) mj = fmaxf(mj, sjv[x]);
        mj = fmaxf(mj, __shfl_xor(mj, 16, 64));
        mj = fmaxf(mj, __shfl_xor(mj, 32, 64));

        float mx[8];
        #pragma unroll
        for (int nt = 0; nt < 8; ++nt) mx[nt] = -1e30f;

        #pragma unroll
        for (int mt = 0; mt < 4; ++mt) {
            const int row = mt * 16 + lr;
            const float si = sSi[row];
            const float mi = lrelu(si + mj);
            f16x8 ap0, ap1;
            float lsum = 0.f;
            #pragma unroll
            for (int jj = 0; jj < 8; ++jj) {
                float p = __expf(lrelu(si + sjv[jj]) - mi);
                f16 ph = (f16)p; lsum += (float)ph; ap0[jj] = ph;
                p = __expf(lrelu(si + sjv[8 + jj]) - mi);
                ph = (f16)p; lsum += (float)ph; ap1[jj] = ph;
            }
            lsum += __shfl_xor(lsum, 16, 64);
            lsum += __shfl_xor(lsum, 32, 64);
            const float inv = 1.0f / lsum;

            f32x4 acc[8];
            #pragma unroll
            for (int nt = 0; nt < 8; ++nt) {
                const int feat = nt * 16 + lr;
                f16x8 bh0 = *(const f16x8*)&sMain[feat * 64 + ((lq ^ (feat & 7)) << 3)];
                f16x8 bh1 = *(const f16x8*)&sMain[feat * 64 + (((4 + lq) ^ (feat & 7)) << 3)];
                acc[nt] = (f32x4){0.f, 0.f, 0.f, 0.f};
                acc[nt] = __builtin_amdgcn_mfma_f32_16x16x32_f16(ap0, bh0, acc[nt], 0, 0, 0);
                acc[nt] = __builtin_amdgcn_mfma_f32_16x16x32_f16(ap1, bh1, acc[nt], 0, 0, 0);
            }
            float invr[4];
            #pragma unroll
            for (int r = 0; r < 4; ++r) invr[r] = __shfl(inv, lq * 4 + r, 64);
            #pragma unroll
            for (int nt = 0; nt < 8; ++nt) {
                #pragma unroll
                for (int r = 0; r < 4; ++r)
                    mx[nt] = fmaxf(mx[nt], acc[nt][r] * invr[r]);
            }
        }
        #pragma unroll
        for (int nt = 0; nt < 8; ++nt) {
            mx[nt] = fmaxf(mx[nt], __shfl_xor(mx[nt], 16, 64));
            mx[nt] = fmaxf(mx[nt], __shfl_xor(mx[nt], 32, 64));
        }
        if (lq == 0) {
            #pragma unroll
            for (int nt = 0; nt < 8; ++nt)
                sPool[nt * 16 + lr] = elu1(mx[nt]);   // elu after max: monotone
        }
    }
    __syncthreads();

    // ================= Readout MLP (per-wave, fp32) ================================
    {
        const int o = lane & 31, half = lane >> 5;
        float s = 0.f;
        #pragma unroll 8
        for (int kk = 0; kk < 64; ++kk) {
            const int c = half * 64 + kk;
            s = fmaf(sPool[c], mw1[c * 32 + o], s);
        }
        s += __shfl_xor(s, 32, 64);
        s = fmaxf(s + mb1[o], 0.0f);
        if (lane < 32) sHid[lane] = s;
    }
    __syncthreads();
    {
        float sA = mb2[lane], sB = mb2[64 + lane];
        #pragma unroll 8
        for (int q = 0; q < 32; ++q) {
            const float h = sHid[q];
            sA = fmaf(h, mw2[q * 128 + lane], sA);
            sB = fmaf(h, mw2[q * 128 + 64 + lane], sB);
        }
        const float rA = fmaxf(sA, 0.0f) + 1e-6f;   // raw_delta[lane]
        const float rB = fmaxf(sB, 0.0f) + 1e-6f;   // raw_power[lane]
        float sumA = rA, sumB = rB;
        #pragma unroll
        for (int m = 1; m < 64; m <<= 1) {
            sumA += __shfl_xor(sumA, m, 64);
            sumB += __shfl_xor(sumB, m, 64);
        }
        out[b * 64 + lane]        = rB / (sumB + 1e-6f);            // power (PMAX = 1)
        out[OUT2 + b * 64 + lane] = 98.425f * rA / (sumA + 1e-6f);  // delta (Bmax = 98.425)
    }
}

extern "C" void kernel_launch(void* const* d_in, const int* in_sizes, int n_in,
                              void* d_out, int out_size, void* d_ws, size_t ws_size,
                              hipStream_t stream) {
    const float* users = (const float*)d_in[0];
    const float* W1    = (const float*)d_in[1];
    const float* a1    = (const float*)d_in[2];
    const float* W2    = (const float*)d_in[3];
    const float* a2    = (const float*)d_in[4];
    const float* mw1   = (const float*)d_in[5];
    const float* mb1   = (const float*)d_in[6];
    const float* mw2   = (const float*)d_in[7];
    const float* mb2   = (const float*)d_in[8];
    float* out = (float*)d_out;
    f16* w2t = (f16*)d_ws;

    w2t_prep<<<64, 256, 0, stream>>>(W2, w2t);
    gat_kernel<<<NBATCH, 64, 0, stream>>>(users, W1, a1, a2, w2t,
                                          mw1, mb1, mw2, mb2, out);
}

// Round 8
// 130.585 us; speedup vs baseline: 1.8741x; 1.0953x over previous
//
#include <hip/hip_runtime.h>

#define NBATCH 4096
#define OUT2 (NBATCH * 64)

typedef _Float16 f16;
typedef __attribute__((ext_vector_type(8))) _Float16 f16x8;
typedef __attribute__((ext_vector_type(4))) _Float16 f16x4;
typedef __attribute__((ext_vector_type(4))) float f32x4;

__device__ __forceinline__ float lrelu(float x) { return x > 0.0f ? x : 0.2f * x; }
__device__ __forceinline__ float elu1(float x)  { return x > 0.0f ? x : __expf(x) - 1.0f; }

// ---------------- prep ----------------
// ws layout: [0,32768) w2b: W2 as f16 MFMA B-frags  w2b[((F2T*4+kf)*64+lane)*8+j] = W2[kf*32+lq*8+j][F2T*16+lr]
//            [32768,33792) w2a f32[256] = {W2 @ a2[:128], W2 @ a2[128:]}
//            [33792,33816) w1a f32[6]   = {W1^T @ a1[:128] (3), W1^T @ a1[128:] (3)}
__global__ void prep(const float* __restrict__ W2, const float* __restrict__ W1,
                     const float* __restrict__ a1, const float* __restrict__ a2,
                     f16* __restrict__ w2b, float* __restrict__ w2a, float* __restrict__ w1a) {
    const int flat = blockIdx.x * 256 + threadIdx.x;   // 0..16383
    const int slot = flat >> 3, j = flat & 7;
    const int F2T = slot >> 8, kf = (slot >> 6) & 3, ln = slot & 63;
    const int lq = ln >> 4, lr = ln & 15;
    w2b[flat] = (f16)W2[(kf * 32 + lq * 8 + j) * 128 + F2T * 16 + lr];
    if (blockIdx.x == 0) {
        if (threadIdx.x < 128) {
            const int f1 = threadIdx.x;
            float si = 0.f, sj = 0.f;
            for (int f2 = 0; f2 < 128; ++f2) {
                const float w = W2[f1 * 128 + f2];
                si = fmaf(w, a2[f2], si);
                sj = fmaf(w, a2[128 + f2], sj);
            }
            w2a[f1] = si; w2a[128 + f1] = sj;
        } else if (threadIdx.x < 131) {
            const int c = threadIdx.x - 128;
            float si = 0.f, sj = 0.f;
            for (int f = 0; f < 128; ++f) {
                const float w = W1[c * 128 + f];
                si = fmaf(w, a1[f], si);
                sj = fmaf(w, a1[128 + f], sj);
            }
            w1a[c] = si; w1a[3 + c] = sj;
        }
    }
}

// sMain (8 KB): [feat_local 0..63][node 0..63] f16, 8-groups XOR-swizzled by (fl&7)
// sBn   (2 KB): [node_local 0..15][feat_local 0..63] f16, swizzled by (nl&7); overlaid by sPool/sHid after E0
__global__ __launch_bounds__(64)
void gat_kernel(const float* __restrict__ users,
                const float* __restrict__ W1,
                const f16* __restrict__ w2b,
                const float* __restrict__ w1a,
                const float* __restrict__ w2a,
                const float* __restrict__ mw1,
                const float* __restrict__ mb1,
                const float* __restrict__ mw2,
                const float* __restrict__ mb2,
                float* __restrict__ out)
{
    const int b = blockIdx.x;
    const int lane = threadIdx.x;      // one wave per block, one batch per wave
    const int lr = lane & 15;
    const int lq = lane >> 4;

    __shared__ __align__(16) char smem[10752];
    f16*   sMain = (f16*)smem;                 // 8192 B
    f16*   sBn   = (f16*)(smem + 8192);        // 2048 B (bounce)
    float* sPool = (float*)(smem + 8192);      // overlay: live after E0 only
    float* sHid  = (float*)(smem + 8704);
    float* sSi   = (float*)(smem + 10240);     // 64 f32
    float* sSj   = (float*)(smem + 10496);     // 64 f32

    // ---- scores layer 1: rank-3 (exact fp32) ----
    {
        const float* u = users + b * 192;
        const float x = u[lane * 3], y = u[lane * 3 + 1], z = u[lane * 3 + 2];
        sSi[lane] = fmaf(x, w1a[0], fmaf(y, w1a[1], z * w1a[2]));
        sSj[lane] = fmaf(x, w1a[3], fmaf(y, w1a[4], z * w1a[5]));
    }
    __syncthreads();
    float mj;
    {
        float v = sSj[lane];
        #pragma unroll
        for (int m = 1; m < 64; m <<= 1) v = fmaxf(v, __shfl_xor(v, m, 64));
        mj = v;
    }

    f16x8 hf[4][4];    // h1 as A/B-frags: [node-tile][k-frag], 64 VGPRs

    // ================= B' + E0 per feat-half =================
    #pragma unroll
    for (int h = 0; h < 2; ++h) {
        // B': Wh1[:, h*64..] = users @ W1 (K=3 zero-padded MFMA)
        f16x8 bw[4];
        #pragma unroll
        for (int ntl = 0; ntl < 4; ++ntl) {
            #pragma unroll
            for (int j = 0; j < 8; ++j) bw[ntl][j] = (f16)0.f;
            if (lq == 0) {
                #pragma unroll
                for (int j = 0; j < 3; ++j)
                    bw[ntl][j] = (f16)W1[j * 128 + h * 64 + ntl * 16 + lr];
            }
        }
        #pragma unroll
        for (int mt = 0; mt < 4; ++mt) {
            f16x8 af;
            #pragma unroll
            for (int j = 0; j < 8; ++j) af[j] = (f16)0.f;
            if (lq == 0) {
                const float* up = users + b * 192 + (mt * 16 + lr) * 3;
                af[0] = (f16)up[0]; af[1] = (f16)up[1]; af[2] = (f16)up[2];
            }
            #pragma unroll
            for (int ntl = 0; ntl < 4; ++ntl) {
                f32x4 acc = (f32x4){0.f, 0.f, 0.f, 0.f};
                acc = __builtin_amdgcn_mfma_f32_16x16x32_f16(af, bw[ntl], acc, 0, 0, 0);
                const int fl = ntl * 16 + lr;                  // node = mt*16+lq*4+r
                const int g = mt * 2 + (lq >> 1);
                const int base = fl * 64 + ((g ^ (fl & 7)) << 3) + ((lq & 1) * 4);
                f16x4 hv;
                #pragma unroll
                for (int r = 0; r < 4; ++r) hv[r] = (f16)acc[r];
                *(f16x4*)&sMain[base] = hv;
            }
        }
        __syncthreads();

        // E0: h1-half = elu(softmax(P1) @ Wh1-half); bounce each 16-node slab -> hf frags
        #pragma unroll
        for (int mt = 0; mt < 4; ++mt) {
            const float si = sSi[mt * 16 + lr];
            const float mi = lrelu(si + mj);
            f16x8 ap0, ap1;
            float lsum = 0.f;
            #pragma unroll
            for (int jj = 0; jj < 8; ++jj) {
                float p = __expf(lrelu(si + sSj[lq * 8 + jj]) - mi);
                f16 ph = (f16)p; lsum += (float)ph; ap0[jj] = ph;
                p = __expf(lrelu(si + sSj[32 + lq * 8 + jj]) - mi);
                ph = (f16)p; lsum += (float)ph; ap1[jj] = ph;
            }
            lsum += __shfl_xor(lsum, 16, 64);
            lsum += __shfl_xor(lsum, 32, 64);
            const float inv = 1.0f / lsum;
            float invr[4];
            #pragma unroll
            for (int r = 0; r < 4; ++r) invr[r] = __shfl(inv, lq * 4 + r, 64);

            f32x4 acc[4];
            #pragma unroll
            for (int ntl = 0; ntl < 4; ++ntl) {
                const int fl = ntl * 16 + lr;
                f16x8 b0 = *(const f16x8*)&sMain[fl * 64 + ((lq ^ (fl & 7)) << 3)];
                f16x8 b1 = *(const f16x8*)&sMain[fl * 64 + (((4 + lq) ^ (fl & 7)) << 3)];
                acc[ntl] = (f32x4){0.f, 0.f, 0.f, 0.f};
                acc[ntl] = __builtin_amdgcn_mfma_f32_16x16x32_f16(ap0, b0, acc[ntl], 0, 0, 0);
                acc[ntl] = __builtin_amdgcn_mfma_f32_16x16x32_f16(ap1, b1, acc[ntl], 0, 0, 0);
            }
            __syncthreads();       // prior slab's bounce reads done
            #pragma unroll
            for (int ntl = 0; ntl < 4; ++ntl) {
                const int fl = ntl * 16 + lr;
                #pragma unroll
                for (int r = 0; r < 4; ++r) {
                    const int nl = lq * 4 + r;
                    const float v = elu1(acc[ntl][r] * invr[r]);
                    sBn[nl * 64 + (((fl >> 3) ^ (nl & 7)) << 3) + (fl & 7)] = (f16)v;
                }
            }
            __syncthreads();
            #pragma unroll
            for (int ksl = 0; ksl < 2; ++ksl)
                hf[mt][h * 2 + ksl] =
                    *(const f16x8*)&sBn[lr * 64 + (((ksl * 4 + lq) ^ (lr & 7)) << 3)];
        }
        __syncthreads();   // all sMain reads done before next half overwrites
    }

    // ---- scores layer 2: s2 = h1 . (W2 @ a2) from hf registers ----
    {
        float s2i[4] = {0.f, 0.f, 0.f, 0.f}, s2j[4] = {0.f, 0.f, 0.f, 0.f};
        #pragma unroll
        for (int ks = 0; ks < 4; ++ks) {
            float wi[8], wj[8];
            *(float4*)&wi[0] = *(const float4*)&w2a[ks * 32 + lq * 8];
            *(float4*)&wi[4] = *(const float4*)&w2a[ks * 32 + lq * 8 + 4];
            *(float4*)&wj[0] = *(const float4*)&w2a[128 + ks * 32 + lq * 8];
            *(float4*)&wj[4] = *(const float4*)&w2a[128 + ks * 32 + lq * 8 + 4];
            #pragma unroll
            for (int mt = 0; mt < 4; ++mt) {
                #pragma unroll
                for (int jj = 0; jj < 8; ++jj) {
                    const float v = (float)hf[mt][ks][jj];
                    s2i[mt] = fmaf(v, wi[jj], s2i[mt]);
                    s2j[mt] = fmaf(v, wj[jj], s2j[mt]);
                }
            }
        }
        #pragma unroll
        for (int mt = 0; mt < 4; ++mt) {
            s2i[mt] += __shfl_xor(s2i[mt], 16, 64);
            s2i[mt] += __shfl_xor(s2i[mt], 32, 64);
            s2j[mt] += __shfl_xor(s2j[mt], 16, 64);
            s2j[mt] += __shfl_xor(s2j[mt], 32, 64);
        }
        if (lq == 0) {
            #pragma unroll
            for (int mt = 0; mt < 4; ++mt) {
                sSi[mt * 16 + lr] = s2i[mt];
                sSj[mt * 16 + lr] = s2j[mt];
            }
        }
        __syncthreads();
    }
    float mj2;
    {
        float v = sSj[lane];
        #pragma unroll
        for (int m = 1; m < 64; m <<= 1) v = fmaxf(v, __shfl_xor(v, m, 64));
        mj2 = v;
    }

    // ================= F'' + E1 per f2-half =================
    #pragma unroll
    for (int h = 0; h < 2; ++h) {
        // F'': Wh2[:, h*64..] = h1 @ W2 (A = hf regs, B = w2b pre-swizzled global)
        #pragma unroll
        for (int f2t = 0; f2t < 4; ++f2t) {
            f16x8 bw2[4];
            #pragma unroll
            for (int kf = 0; kf < 4; ++kf)
                bw2[kf] = *(const f16x8*)(w2b + (((h * 4 + f2t) * 4 + kf) * 64 + lane) * 8);
            #pragma unroll
            for (int ntile = 0; ntile < 4; ++ntile) {
                f32x4 acc = (f32x4){0.f, 0.f, 0.f, 0.f};
                #pragma unroll
                for (int kf = 0; kf < 4; ++kf)
                    acc = __builtin_amdgcn_mfma_f32_16x16x32_f16(hf[ntile][kf], bw2[kf], acc, 0, 0, 0);
                const int fl = f2t * 16 + lr;                  // node = ntile*16+lq*4+r
                const int g = ntile * 2 + (lq >> 1);
                const int base = fl * 64 + ((g ^ (fl & 7)) << 3) + ((lq & 1) * 4);
                f16x4 hv;
                #pragma unroll
                for (int r = 0; r < 4; ++r) hv[r] = (f16)acc[r];
                *(f16x4*)&sMain[base] = hv;
            }
        }
        __syncthreads();

        // E1: h2-half + register max-pool
        float mx[4] = {-1e30f, -1e30f, -1e30f, -1e30f};
        #pragma unroll
        for (int mt = 0; mt < 4; ++mt) {
            const float si = sSi[mt * 16 + lr];
            const float mi = lrelu(si + mj2);
            f16x8 ap0, ap1;
            float lsum = 0.f;
            #pragma unroll
            for (int jj = 0; jj < 8; ++jj) {
                float p = __expf(lrelu(si + sSj[lq * 8 + jj]) - mi);
                f16 ph = (f16)p; lsum += (float)ph; ap0[jj] = ph;
                p = __expf(lrelu(si + sSj[32 + lq * 8 + jj]) - mi);
                ph = (f16)p; lsum += (float)ph; ap1[jj] = ph;
            }
            lsum += __shfl_xor(lsum, 16, 64);
            lsum += __shfl_xor(lsum, 32, 64);
            const float inv = 1.0f / lsum;
            float invr[4];
            #pragma unroll
            for (int r = 0; r < 4; ++r) invr[r] = __shfl(inv, lq * 4 + r, 64);
            #pragma unroll
            for (int ntl = 0; ntl < 4; ++ntl) {
                const int fl = ntl * 16 + lr;
                f16x8 b0 = *(const f16x8*)&sMain[fl * 64 + ((lq ^ (fl & 7)) << 3)];
                f16x8 b1 = *(const f16x8*)&sMain[fl * 64 + (((4 + lq) ^ (fl & 7)) << 3)];
                f32x4 acc = (f32x4){0.f, 0.f, 0.f, 0.f};
                acc = __builtin_amdgcn_mfma_f32_16x16x32_f16(ap0, b0, acc, 0, 0, 0);
                acc = __builtin_amdgcn_mfma_f32_16x16x32_f16(ap1, b1, acc, 0, 0, 0);
                #pragma unroll
                for (int r = 0; r < 4; ++r)
                    mx[ntl] = fmaxf(mx[ntl], acc[r] * invr[r]);
            }
        }
        #pragma unroll
        for (int ntl = 0; ntl < 4; ++ntl) {
            mx[ntl] = fmaxf(mx[ntl], __shfl_xor(mx[ntl], 16, 64));
            mx[ntl] = fmaxf(mx[ntl], __shfl_xor(mx[ntl], 32, 64));
        }
        if (lq == 0) {
            #pragma unroll
            for (int ntl = 0; ntl < 4; ++ntl)
                sPool[h * 64 + ntl * 16 + lr] = elu1(mx[ntl]);   // elu after max (monotone)
        }
        __syncthreads();
    }

    // ================= Readout (per-wave, fp32) =================
    {
        const int o = lane & 31, hh = lane >> 5;
        float s = 0.f;
        #pragma unroll 8
        for (int kk = 0; kk < 64; ++kk) {
            const int c = hh * 64 + kk;
            s = fmaf(sPool[c], mw1[c * 32 + o], s);
        }
        s += __shfl_xor(s, 32, 64);
        s = fmaxf(s + mb1[o], 0.0f);
        if (lane < 32) sHid[lane] = s;
    }
    __syncthreads();
    {
        float sA = mb2[lane], sB = mb2[64 + lane];
        #pragma unroll 8
        for (int q = 0; q < 32; ++q) {
            const float hq = sHid[q];
            sA = fmaf(hq, mw2[q * 128 + lane], sA);
            sB = fmaf(hq, mw2[q * 128 + 64 + lane], sB);
        }
        const float rA = fmaxf(sA, 0.0f) + 1e-6f;   // raw_delta[lane]
        const float rB = fmaxf(sB, 0.0f) + 1e-6f;   // raw_power[lane]
        float sumA = rA, sumB = rB;
        #pragma unroll
        for (int m = 1; m < 64; m <<= 1) {
            sumA += __shfl_xor(sumA, m, 64);
            sumB += __shfl_xor(sumB, m, 64);
        }
        out[b * 64 + lane]        = rB / (sumB + 1e-6f);            // power (PMAX = 1)
        out[OUT2 + b * 64 + lane] = 98.425f * rA / (sumA + 1e-6f);  // delta (Bmax = 98.425)
    }
}

extern "C" void kernel_launch(void* const* d_in, const int* in_sizes, int n_in,
                              void* d_out, int out_size, void* d_ws, size_t ws_size,
                              hipStream_t stream) {
    const float* users = (const float*)d_in[0];
    const float* W1    = (const float*)d_in[1];
    const float* a1    = (const float*)d_in[2];
    const float* W2    = (const float*)d_in[3];
    const float* a2    = (const float*)d_in[4];
    const float* mw1   = (const float*)d_in[5];
    const float* mb1   = (const float*)d_in[6];
    const float* mw2   = (const float*)d_in[7];
    const float* mb2   = (const float*)d_in[8];
    float* out = (float*)d_out;

    f16*   w2b = (f16*)d_ws;
    float* w2a = (float*)((char*)d_ws + 32768);
    float* w1a = (float*)((char*)d_ws + 33792);

    prep<<<64, 256, 0, stream>>>(W2, W1, a1, a2, w2b, w2a, w1a);
    gat_kernel<<<NBATCH, 64, 0, stream>>>(users, W1, w2b, w1a, w2a,
                                          mw1, mb1, mw2, mb2, out);
}

// Round 9
// 121.469 us; speedup vs baseline: 2.0148x; 1.0750x over previous
//
#include <hip/hip_runtime.h>

#define NBATCH 4096
#define OUT2 (NBATCH * 64)

typedef _Float16 f16;
typedef __attribute__((ext_vector_type(8))) _Float16 f16x8;
typedef __attribute__((ext_vector_type(4))) _Float16 f16x4;
typedef __attribute__((ext_vector_type(4))) float f32x4;

__device__ __forceinline__ float lrelu(float x) { return x > 0.0f ? x : 0.2f * x; }
__device__ __forceinline__ float elu1(float x)  { return x > 0.0f ? x : __expf(x) - 1.0f; }

// ---------------- prep ----------------
// ws: [0,32768) w2b f16 MFMA B-frags: w2b[((F2T*4+kf)*64+ln)*8+j] = W2[kf*32+(ln>>4)*8+j][F2T*16+(ln&15)]
//     [32768,33792) w2a f32[256] = {W2@a2[:128], W2@a2[128:]}
//     [33792,33816) w1a f32[6]   = {W1^T@a1[:128] (3), W1^T@a1[128:] (3)}
__global__ void prep(const float* __restrict__ W2, const float* __restrict__ W1,
                     const float* __restrict__ a1, const float* __restrict__ a2,
                     f16* __restrict__ w2b, float* __restrict__ w2a, float* __restrict__ w1a) {
    const int flat = blockIdx.x * 256 + threadIdx.x;   // 0..16383
    const int slot = flat >> 3, j = flat & 7;
    const int F2T = slot >> 8, kf = (slot >> 6) & 3, ln = slot & 63;
    const int lq = ln >> 4, lr = ln & 15;
    w2b[flat] = (f16)W2[(kf * 32 + lq * 8 + j) * 128 + F2T * 16 + lr];
    if (blockIdx.x == 0) {
        if (threadIdx.x < 128) {
            const int f1 = threadIdx.x;
            float si = 0.f, sj = 0.f;
            for (int f2 = 0; f2 < 128; ++f2) {
                const float w = W2[f1 * 128 + f2];
                si = fmaf(w, a2[f2], si);
                sj = fmaf(w, a2[128 + f2], sj);
            }
            w2a[f1] = si; w2a[128 + f1] = sj;
        } else if (threadIdx.x < 131) {
            const int c = threadIdx.x - 128;
            float si = 0.f, sj = 0.f;
            for (int f = 0; f < 128; ++f) {
                const float w = W1[c * 128 + f];
                si = fmaf(w, a1[f], si);
                sj = fmaf(w, a1[128 + f], sj);
            }
            w1a[c] = si; w1a[3 + c] = sj;
        }
    }
}

// sMain (8 KB): dual-role.
//  - layer-1 bounce: h1[node n][feat_local fl] : n*64 + (((fl>>3)^(n&7))<<3) + (fl&7)
//  - layer-2 Wh2:    [feat fl][node n]         : fl*64 + (((n>>3)^(fl&7))<<3) + (n&7)
__global__ __launch_bounds__(64)
void gat_kernel(const float* __restrict__ users,
                const float* __restrict__ W1,
                const f16* __restrict__ w2b,
                const float* __restrict__ w1a,
                const float* __restrict__ w2a,
                const float* __restrict__ mw1,
                const float* __restrict__ mb1,
                const float* __restrict__ mw2,
                const float* __restrict__ mb2,
                float* __restrict__ out)
{
    const int b = blockIdx.x;
    const int lane = threadIdx.x;      // one wave per block, one batch per wave
    const int lr = lane & 15;
    const int lq = lane >> 4;

    __shared__ __align__(16) char smem[9344];
    f16*   sMain = (f16*)smem;                 // 8192 B
    float* sSi   = (float*)(smem + 8192);      // 64 f32
    float* sSj   = (float*)(smem + 8448);      // 64 f32
    float* sPool = (float*)(smem + 8704);      // 128 f32
    float* sHid  = (float*)(smem + 9216);      // 32 f32

    // ---- scores layer 1: rank-3 (exact fp32) ----
    {
        const float* u = users + b * 192;
        const float x = u[lane * 3], y = u[lane * 3 + 1], z = u[lane * 3 + 2];
        sSi[lane] = fmaf(x, w1a[0], fmaf(y, w1a[1], z * w1a[2]));
        sSj[lane] = fmaf(x, w1a[3], fmaf(y, w1a[4], z * w1a[5]));
    }
    __syncthreads();
    float mj;
    {
        float v = sSj[lane];
        #pragma unroll
        for (int m = 1; m < 64; m <<= 1) v = fmaxf(v, __shfl_xor(v, m, 64));
        mj = v;
    }

    // ---- softmax-1 fragments (built ONCE) + per-lane inverse denominators ----
    f16x8 ap[4][2];     // P as B-frags: B[k=j][n=i_local], i = mt*16+lr
    float inv1[4];
    #pragma unroll
    for (int mt = 0; mt < 4; ++mt) {
        const float si = sSi[mt * 16 + lr];
        const float mi = lrelu(si + mj);
        float lsum = 0.f;
        #pragma unroll
        for (int jj = 0; jj < 8; ++jj) {
            float p = __expf(lrelu(si + sSj[lq * 8 + jj]) - mi);
            f16 ph = (f16)p; lsum += (float)ph; ap[mt][0][jj] = ph;
            p = __expf(lrelu(si + sSj[32 + lq * 8 + jj]) - mi);
            ph = (f16)p; lsum += (float)ph; ap[mt][1][jj] = ph;
        }
        lsum += __shfl_xor(lsum, 16, 64);
        lsum += __shfl_xor(lsum, 32, 64);
        inv1[mt] = 1.0f / lsum;            // row i = mt*16+lr (per-lane!)
    }

    // ---- product-1: PU^T = U^T @ P^T  (D[c][i]) ----
    f16x8 af2[2];    // U^T A-frags: A[m=c][k=node], rows c=lr (only lr<3 valid)
    #pragma unroll
    for (int ks = 0; ks < 2; ++ks) {
        #pragma unroll
        for (int jj = 0; jj < 8; ++jj) {
            const int node = ks * 32 + lq * 8 + jj;
            af2[ks][jj] = (lr < 3) ? (f16)users[b * 192 + node * 3 + lr] : (f16)0.f;
        }
    }
    f32x4 d1[4];
    #pragma unroll
    for (int nt = 0; nt < 4; ++nt) {
        d1[nt] = (f32x4){0.f, 0.f, 0.f, 0.f};
        d1[nt] = __builtin_amdgcn_mfma_f32_16x16x32_f16(af2[0], ap[nt][0], d1[nt], 0, 0, 0);
        d1[nt] = __builtin_amdgcn_mfma_f32_16x16x32_f16(af2[1], ap[nt][1], d1[nt], 0, 0, 0);
    }
    // PU^T as B-frags: B[k=c][n=i_local]; source lane = lr (c lives in r of lane lr)
    f16x8 bfr[4];
    #pragma unroll
    for (int nt = 0; nt < 4; ++nt) {
        const float c0 = __shfl(d1[nt][0], lr, 64);
        const float c1 = __shfl(d1[nt][1], lr, 64);
        const float c2 = __shfl(d1[nt][2], lr, 64);
        #pragma unroll
        for (int jj = 0; jj < 8; ++jj) bfr[nt][jj] = (f16)0.f;
        if (lq == 0) {
            bfr[nt][0] = (f16)c0; bfr[nt][1] = (f16)c1; bfr[nt][2] = (f16)c2;
        }
    }

    // ================= layer-1 halves: h1^T = W1^T @ PU^T -> bounce -> hf =========
    f16x8 hf[4][4];    // h1 as A-frags for F: [node-tile][k-frag]
    #pragma unroll
    for (int h = 0; h < 2; ++h) {
        __syncthreads();    // bounce region reuse across halves
        #pragma unroll
        for (int ftl = 0; ftl < 4; ++ftl) {
            f16x8 af3;      // W1^T A-frag: A[m=f][k=c], f = (h*4+ftl)*16+lr
            #pragma unroll
            for (int jj = 0; jj < 8; ++jj) af3[jj] = (f16)0.f;
            if (lq == 0) {
                #pragma unroll
                for (int jj = 0; jj < 3; ++jj)
                    af3[jj] = (f16)W1[jj * 128 + (h * 4 + ftl) * 16 + lr];
            }
            #pragma unroll
            for (int nt = 0; nt < 4; ++nt) {
                f32x4 acc = (f32x4){0.f, 0.f, 0.f, 0.f};
                acc = __builtin_amdgcn_mfma_f32_16x16x32_f16(af3, bfr[nt], acc, 0, 0, 0);
                // D[f = (h*4+ftl)*16+lq*4+r][i = nt*16+lr]; inv per-lane, elu, b64 store
                f16x4 hv;
                #pragma unroll
                for (int r = 0; r < 4; ++r) hv[r] = (f16)elu1(acc[r] * inv1[nt]);
                const int n = nt * 16 + lr;
                const int g = 2 * ftl + (lq >> 1);
                *(f16x4*)&sMain[n * 64 + ((g ^ (n & 7)) << 3) + ((lq & 1) * 4)] = hv;
            }
        }
        __syncthreads();
        #pragma unroll
        for (int nt = 0; nt < 4; ++nt) {
            const int n = nt * 16 + lr;
            #pragma unroll
            for (int ksl = 0; ksl < 2; ++ksl)
                hf[nt][h * 2 + ksl] =
                    *(const f16x8*)&sMain[n * 64 + (((ksl * 4 + lq) ^ (n & 7)) << 3)];
        }
    }

    // ---- scores layer 2: s2 = h1 . (W2 @ a2) from hf registers ----
    {
        float s2i[4] = {0.f, 0.f, 0.f, 0.f}, s2j[4] = {0.f, 0.f, 0.f, 0.f};
        #pragma unroll
        for (int ks = 0; ks < 4; ++ks) {
            float wi[8], wj[8];
            *(float4*)&wi[0] = *(const float4*)&w2a[ks * 32 + lq * 8];
            *(float4*)&wi[4] = *(const float4*)&w2a[ks * 32 + lq * 8 + 4];
            *(float4*)&wj[0] = *(const float4*)&w2a[128 + ks * 32 + lq * 8];
            *(float4*)&wj[4] = *(const float4*)&w2a[128 + ks * 32 + lq * 8 + 4];
            #pragma unroll
            for (int mt = 0; mt < 4; ++mt) {
                #pragma unroll
                for (int jj = 0; jj < 8; ++jj) {
                    const float v = (float)hf[mt][ks][jj];
                    s2i[mt] = fmaf(v, wi[jj], s2i[mt]);
                    s2j[mt] = fmaf(v, wj[jj], s2j[mt]);
                }
            }
        }
        #pragma unroll
        for (int mt = 0; mt < 4; ++mt) {
            s2i[mt] += __shfl_xor(s2i[mt], 16, 64);
            s2i[mt] += __shfl_xor(s2i[mt], 32, 64);
            s2j[mt] += __shfl_xor(s2j[mt], 16, 64);
            s2j[mt] += __shfl_xor(s2j[mt], 32, 64);
        }
        if (lq == 0) {
            #pragma unroll
            for (int mt = 0; mt < 4; ++mt) {
                sSi[mt * 16 + lr] = s2i[mt];
                sSj[mt * 16 + lr] = s2j[mt];
            }
        }
        __syncthreads();
    }
    float mj2;
    {
        float v = sSj[lane];
        #pragma unroll
        for (int m = 1; m < 64; m <<= 1) v = fmaxf(v, __shfl_xor(v, m, 64));
        mj2 = v;
    }

    // ---- softmax-2 fragments (built ONCE) + per-lane inverses ----
    f16x8 ap2[4][2];
    float inv2[4];
    #pragma unroll
    for (int mt = 0; mt < 4; ++mt) {
        const float si = sSi[mt * 16 + lr];
        const float mi = lrelu(si + mj2);
        float lsum = 0.f;
        #pragma unroll
        for (int jj = 0; jj < 8; ++jj) {
            float p = __expf(lrelu(si + sSj[lq * 8 + jj]) - mi);
            f16 ph = (f16)p; lsum += (float)ph; ap2[mt][0][jj] = ph;
            p = __expf(lrelu(si + sSj[32 + lq * 8 + jj]) - mi);
            ph = (f16)p; lsum += (float)ph; ap2[mt][1][jj] = ph;
        }
        lsum += __shfl_xor(lsum, 16, 64);
        lsum += __shfl_xor(lsum, 32, 64);
        inv2[mt] = 1.0f / lsum;
    }

    // ================= F + E1 per f2-half =================
    #pragma unroll
    for (int h = 0; h < 2; ++h) {
        __syncthreads();   // prior sMain readers done
        // F: Wh2-half = h1 @ W2 (A = hf regs, B = w2b pre-swizzled global)
        #pragma unroll
        for (int f2t = 0; f2t < 4; ++f2t) {
            f16x8 bw2[4];
            #pragma unroll
            for (int kf = 0; kf < 4; ++kf)
                bw2[kf] = *(const f16x8*)(w2b + (((h * 4 + f2t) * 4 + kf) * 64 + lane) * 8);
            #pragma unroll
            for (int ntile = 0; ntile < 4; ++ntile) {
                f32x4 acc = (f32x4){0.f, 0.f, 0.f, 0.f};
                #pragma unroll
                for (int kf = 0; kf < 4; ++kf)
                    acc = __builtin_amdgcn_mfma_f32_16x16x32_f16(hf[ntile][kf], bw2[kf], acc, 0, 0, 0);
                const int fl = f2t * 16 + lr;                  // node = ntile*16+lq*4+r
                const int g = ntile * 2 + (lq >> 1);
                f16x4 hv;
                #pragma unroll
                for (int r = 0; r < 4; ++r) hv[r] = (f16)acc[r];
                *(f16x4*)&sMain[fl * 64 + ((g ^ (fl & 7)) << 3) + ((lq & 1) * 4)] = hv;
            }
        }
        __syncthreads();

        // E1 (operand-swapped): D[f][i]; per-lane inv2; register max-pool over i
        #pragma unroll
        for (int ftl = 0; ftl < 4; ++ftl) {
            const int fl = ftl * 16 + lr;
            f16x8 b0 = *(const f16x8*)&sMain[fl * 64 + ((lq ^ (fl & 7)) << 3)];
            f16x8 b1 = *(const f16x8*)&sMain[fl * 64 + (((4 + lq) ^ (fl & 7)) << 3)];
            f32x4 mx4 = (f32x4){-1e30f, -1e30f, -1e30f, -1e30f};
            #pragma unroll
            for (int mt = 0; mt < 4; ++mt) {
                f32x4 acc = (f32x4){0.f, 0.f, 0.f, 0.f};
                acc = __builtin_amdgcn_mfma_f32_16x16x32_f16(b0, ap2[mt][0], acc, 0, 0, 0);
                acc = __builtin_amdgcn_mfma_f32_16x16x32_f16(b1, ap2[mt][1], acc, 0, 0, 0);
                #pragma unroll
                for (int r = 0; r < 4; ++r)
                    mx4[r] = fmaxf(mx4[r], acc[r] * inv2[mt]);
            }
            // reduce over the 16 lanes (lr) sharing this lq group
            #pragma unroll
            for (int m = 1; m < 16; m <<= 1) {
                #pragma unroll
                for (int r = 0; r < 4; ++r)
                    mx4[r] = fmaxf(mx4[r], __shfl_xor(mx4[r], m, 64));
            }
            if (lr == 0) {
                float4 pv;
                pv.x = elu1(mx4[0]); pv.y = elu1(mx4[1]);
                pv.z = elu1(mx4[2]); pv.w = elu1(mx4[3]);
                *(float4*)&sPool[h * 64 + ftl * 16 + lq * 4] = pv;
            }
        }
        __syncthreads();
    }

    // ================= Readout (per-wave, fp32) =================
    {
        const int o = lane & 31, hh = lane >> 5;
        float s = 0.f;
        #pragma unroll 8
        for (int kk = 0; kk < 64; ++kk) {
            const int c = hh * 64 + kk;
            s = fmaf(sPool[c], mw1[c * 32 + o], s);
        }
        s += __shfl_xor(s, 32, 64);
        s = fmaxf(s + mb1[o], 0.0f);
        if (lane < 32) sHid[lane] = s;
    }
    __syncthreads();
    {
        float sA = mb2[lane], sB = mb2[64 + lane];
        #pragma unroll 8
        for (int q = 0; q < 32; ++q) {
            const float hq = sHid[q];
            sA = fmaf(hq, mw2[q * 128 + lane], sA);
            sB = fmaf(hq, mw2[q * 128 + 64 + lane], sB);
        }
        const float rA = fmaxf(sA, 0.0f) + 1e-6f;   // raw_delta[lane]
        const float rB = fmaxf(sB, 0.0f) + 1e-6f;   // raw_power[lane]
        float sumA = rA, sumB = rB;
        #pragma unroll
        for (int m = 1; m < 64; m <<= 1) {
            sumA += __shfl_xor(sumA, m, 64);
            sumB += __shfl_xor(sumB, m, 64);
        }
        out[b * 64 + lane]        = rB / (sumB + 1e-6f);            // power (PMAX = 1)
        out[OUT2 + b * 64 + lane] = 98.425f * rA / (sumA + 1e-6f);  // delta (Bmax = 98.425)
    }
}

extern "C" void kernel_launch(void* const* d_in, const int* in_sizes, int n_in,
                              void* d_out, int out_size, void* d_ws, size_t ws_size,
                              hipStream_t stream) {
    const float* users = (const float*)d_in[0];
    const float* W1    = (const float*)d_in[1];
    const float* a1    = (const float*)d_in[2];
    const float* W2    = (const float*)d_in[3];
    const float* a2    = (const float*)d_in[4];
    const float* mw1   = (const float*)d_in[5];
    const float* mb1   = (const float*)d_in[6];
    const float* mw2   = (const float*)d_in[7];
    const float* mb2   = (const float*)d_in[8];
    float* out = (float*)d_out;

    f16*   w2b = (f16*)d_ws;
    float* w2a = (float*)((char*)d_ws + 32768);
    float* w1a = (float*)((char*)d_ws + 33792);

    prep<<<64, 256, 0, stream>>>(W2, W1, a1, a2, w2b, w2a, w1a);
    gat_kernel<<<NBATCH, 64, 0, stream>>>(users, W1, w2b, w1a, w2a,
                                          mw1, mb1, mw2, mb2, out);
}

// Round 10
// 117.506 us; speedup vs baseline: 2.0827x; 1.0337x over previous
//
#include <hip/hip_runtime.h>

#define NBATCH 4096
#define OUT2 (NBATCH * 64)

typedef _Float16 f16;
typedef __attribute__((ext_vector_type(8))) _Float16 f16x8;
typedef __attribute__((ext_vector_type(4))) _Float16 f16x4;
typedef __attribute__((ext_vector_type(4))) float f32x4;

__device__ __forceinline__ float lrelu(float x) { return x > 0.0f ? x : 0.2f * x; }
__device__ __forceinline__ float elu1(float x)  { return x > 0.0f ? x : __expf(x) - 1.0f; }

// ---------------- prep ----------------
// ws: [0,32768)      w2b  f16 MFMA B-frags: w2b[((F2T*4+kf)*64+ln)*8+j] = W2[kf*32+(ln>>4)*8+j][F2T*16+(ln&15)]
//     [32768,32792)  w1a  f32[6] = {W1^T@a1[:128] (3), W1^T@a1[128:] (3)}
//     [32800,36896)  w2ab f16 B-frags of [W2@a2[:128] | W2@a2[128:]] (2 cols):
//                    w2ab[(ks*64+ln)*8+jj] = (n<2) ? sum_f2 W2[k][f2]*a2[n*128+f2] : 0,
//                    k = ks*32+(ln>>4)*8+jj, n = ln&15
__global__ void prep(const float* __restrict__ W2, const float* __restrict__ W1,
                     const float* __restrict__ a1, const float* __restrict__ a2,
                     f16* __restrict__ w2b, float* __restrict__ w1a, f16* __restrict__ w2ab) {
    const int flat = blockIdx.x * 256 + threadIdx.x;   // 0..16383
    const int slot = flat >> 3, j = flat & 7;
    const int F2T = slot >> 8, kf = (slot >> 6) & 3, ln = slot & 63;
    const int lq = ln >> 4, lr = ln & 15;
    w2b[flat] = (f16)W2[(kf * 32 + lq * 8 + j) * 128 + F2T * 16 + lr];
    if (flat < 2048) {
        const int ks = flat >> 9, ln2 = (flat >> 3) & 63, jj = flat & 7;
        const int k = ks * 32 + ((ln2 >> 4) & 3) * 8 + jj;
        const int n = ln2 & 15;
        float v = 0.f;
        if (n < 2) {
            const float* av = a2 + n * 128;
            for (int f2 = 0; f2 < 128; ++f2) v = fmaf(W2[k * 128 + f2], av[f2], v);
        }
        w2ab[flat] = (f16)v;
    }
    if (flat >= 16381) {   // last 3 threads: w1a
        const int c = flat - 16381;
        float si = 0.f, sj = 0.f;
        for (int f = 0; f < 128; ++f) {
            const float w = W1[c * 128 + f];
            si = fmaf(w, a1[f], si);
            sj = fmaf(w, a1[128 + f], sj);
        }
        w1a[c] = si; w1a[3 + c] = sj;
    }
}

// sMain (8 KB): dual-role.
//  - layer-1 bounce: h1[node n][feat_local fl] : n*64 + (((fl>>3)^(n&7))<<3) + (fl&7)
//  - layer-2 Wh2:    [feat fl][node n]         : fl*64 + (((n>>3)^(fl&7))<<3) + (n&7)
__global__ __launch_bounds__(64, 3)   // 3 waves/EU: cap total regs ~170 (demand ~160, no spill expected)
void gat_kernel(const float* __restrict__ users,
                const float* __restrict__ W1,
                const f16* __restrict__ w2b,
                const float* __restrict__ w1a,
                const f16* __restrict__ w2ab,
                const float* __restrict__ mw1,
                const float* __restrict__ mb1,
                const float* __restrict__ mw2,
                const float* __restrict__ mb2,
                float* __restrict__ out)
{
    const int b = blockIdx.x;
    const int lane = threadIdx.x;      // one wave per block, one batch per wave
    const int lr = lane & 15;
    const int lq = lane >> 4;

    __shared__ __align__(16) char smem[9344];
    f16*   sMain = (f16*)smem;                 // 8192 B
    float* sSi   = (float*)(smem + 8192);      // 64 f32
    float* sSj   = (float*)(smem + 8448);      // 64 f32
    float* sPool = (float*)(smem + 8704);      // 128 f32
    float* sHid  = (float*)(smem + 9216);      // 32 f32

    // ---- scores layer 1: rank-3 (exact fp32) ----
    {
        const float* u = users + b * 192;
        const float x = u[lane * 3], y = u[lane * 3 + 1], z = u[lane * 3 + 2];
        sSi[lane] = fmaf(x, w1a[0], fmaf(y, w1a[1], z * w1a[2]));
        sSj[lane] = fmaf(x, w1a[3], fmaf(y, w1a[4], z * w1a[5]));
    }
    __syncthreads();
    float mj;
    {
        float v = sSj[lane];
        #pragma unroll
        for (int m = 1; m < 64; m <<= 1) v = fmaxf(v, __shfl_xor(v, m, 64));
        mj = v;
    }

    // ---- softmax-1 fragments (built ONCE) + per-lane inverse denominators ----
    f16x8 ap[4][2];     // P as B-frags: B[k=j][n=i_local], i = mt*16+lr
    float inv1[4];
    #pragma unroll
    for (int mt = 0; mt < 4; ++mt) {
        const float si = sSi[mt * 16 + lr];
        const float mi = lrelu(si + mj);
        float lsum = 0.f;
        #pragma unroll
        for (int jj = 0; jj < 8; ++jj) {
            float p = __expf(lrelu(si + sSj[lq * 8 + jj]) - mi);
            f16 ph = (f16)p; lsum += (float)ph; ap[mt][0][jj] = ph;
            p = __expf(lrelu(si + sSj[32 + lq * 8 + jj]) - mi);
            ph = (f16)p; lsum += (float)ph; ap[mt][1][jj] = ph;
        }
        lsum += __shfl_xor(lsum, 16, 64);
        lsum += __shfl_xor(lsum, 32, 64);
        inv1[mt] = 1.0f / lsum;            // row i = mt*16+lr (per-lane!)
    }

    // ---- product-1: PU^T = U^T @ P^T  (D[c][i]) ----
    f16x8 af2[2];    // U^T A-frags: A[m=c][k=node], rows c=lr (only lr<3 valid)
    #pragma unroll
    for (int ks = 0; ks < 2; ++ks) {
        #pragma unroll
        for (int jj = 0; jj < 8; ++jj) {
            const int node = ks * 32 + lq * 8 + jj;
            af2[ks][jj] = (lr < 3) ? (f16)users[b * 192 + node * 3 + lr] : (f16)0.f;
        }
    }
    f32x4 d1[4];
    #pragma unroll
    for (int nt = 0; nt < 4; ++nt) {
        d1[nt] = (f32x4){0.f, 0.f, 0.f, 0.f};
        d1[nt] = __builtin_amdgcn_mfma_f32_16x16x32_f16(af2[0], ap[nt][0], d1[nt], 0, 0, 0);
        d1[nt] = __builtin_amdgcn_mfma_f32_16x16x32_f16(af2[1], ap[nt][1], d1[nt], 0, 0, 0);
    }
    // PU^T as B-frags: B[k=c][n=i_local]; source lane = lr (c lives in r of lane lr)
    f16x8 bfr[4];
    #pragma unroll
    for (int nt = 0; nt < 4; ++nt) {
        const float c0 = __shfl(d1[nt][0], lr, 64);
        const float c1 = __shfl(d1[nt][1], lr, 64);
        const float c2 = __shfl(d1[nt][2], lr, 64);
        #pragma unroll
        for (int jj = 0; jj < 8; ++jj) bfr[nt][jj] = (f16)0.f;
        if (lq == 0) {
            bfr[nt][0] = (f16)c0; bfr[nt][1] = (f16)c1; bfr[nt][2] = (f16)c2;
        }
    }

    // ================= layer-1 halves: h1^T = W1^T @ PU^T -> bounce -> hf =========
    f16x8 hf[4][4];    // h1 as A-frags for F: [node-tile][k-frag]
    #pragma unroll
    for (int h = 0; h < 2; ++h) {
        __syncthreads();    // bounce region reuse across halves
        #pragma unroll
        for (int ftl = 0; ftl < 4; ++ftl) {
            f16x8 af3;      // W1^T A-frag: A[m=f][k=c], f = (h*4+ftl)*16+lr
            #pragma unroll
            for (int jj = 0; jj < 8; ++jj) af3[jj] = (f16)0.f;
            if (lq == 0) {
                #pragma unroll
                for (int jj = 0; jj < 3; ++jj)
                    af3[jj] = (f16)W1[jj * 128 + (h * 4 + ftl) * 16 + lr];
            }
            #pragma unroll
            for (int nt = 0; nt < 4; ++nt) {
                f32x4 acc = (f32x4){0.f, 0.f, 0.f, 0.f};
                acc = __builtin_amdgcn_mfma_f32_16x16x32_f16(af3, bfr[nt], acc, 0, 0, 0);
                // D[f = (h*4+ftl)*16+lq*4+r][i = nt*16+lr]; inv per-lane, elu, b64 store
                f16x4 hv;
                #pragma unroll
                for (int r = 0; r < 4; ++r) hv[r] = (f16)elu1(acc[r] * inv1[nt]);
                const int n = nt * 16 + lr;
                const int g = 2 * ftl + (lq >> 1);
                *(f16x4*)&sMain[n * 64 + ((g ^ (n & 7)) << 3) + ((lq & 1) * 4)] = hv;
            }
        }
        __syncthreads();
        #pragma unroll
        for (int nt = 0; nt < 4; ++nt) {
            const int n = nt * 16 + lr;
            #pragma unroll
            for (int ksl = 0; ksl < 2; ++ksl)
                hf[nt][h * 2 + ksl] =
                    *(const f16x8*)&sMain[n * 64 + (((ksl * 4 + lq) ^ (n & 7)) << 3)];
        }
    }

    // ---- scores layer 2 via MFMA: D[m=node][n] = h1 @ [W2a2i | W2a2j] ----
    {
        f32x4 sacc[4];
        #pragma unroll
        for (int mt = 0; mt < 4; ++mt) sacc[mt] = (f32x4){0.f, 0.f, 0.f, 0.f};
        #pragma unroll
        for (int ks = 0; ks < 4; ++ks) {
            f16x8 bsw = *(const f16x8*)(w2ab + (ks * 64 + lane) * 8);
            #pragma unroll
            for (int mt = 0; mt < 4; ++mt)
                sacc[mt] = __builtin_amdgcn_mfma_f32_16x16x32_f16(hf[mt][ks], bsw, sacc[mt], 0, 0, 0);
        }
        if (lr < 2) {
            float* dst = (lr == 0) ? sSi : sSj;
            #pragma unroll
            for (int mt = 0; mt < 4; ++mt) {
                #pragma unroll
                for (int r = 0; r < 4; ++r)
                    dst[mt * 16 + lq * 4 + r] = sacc[mt][r];
            }
        }
        __syncthreads();
    }
    float mj2;
    {
        float v = sSj[lane];
        #pragma unroll
        for (int m = 1; m < 64; m <<= 1) v = fmaxf(v, __shfl_xor(v, m, 64));
        mj2 = v;
    }

    // ---- softmax-2 fragments (built ONCE) + per-lane inverses ----
    f16x8 ap2[4][2];
    float inv2[4];
    #pragma unroll
    for (int mt = 0; mt < 4; ++mt) {
        const float si = sSi[mt * 16 + lr];
        const float mi = lrelu(si + mj2);
        float lsum = 0.f;
        #pragma unroll
        for (int jj = 0; jj < 8; ++jj) {
            float p = __expf(lrelu(si + sSj[lq * 8 + jj]) - mi);
            f16 ph = (f16)p; lsum += (float)ph; ap2[mt][0][jj] = ph;
            p = __expf(lrelu(si + sSj[32 + lq * 8 + jj]) - mi);
            ph = (f16)p; lsum += (float)ph; ap2[mt][1][jj] = ph;
        }
        lsum += __shfl_xor(lsum, 16, 64);
        lsum += __shfl_xor(lsum, 32, 64);
        inv2[mt] = 1.0f / lsum;
    }

    // ================= F + E1 per f2-half =================
    #pragma unroll
    for (int h = 0; h < 2; ++h) {
        __syncthreads();   // prior sMain readers done
        // F: Wh2-half = h1 @ W2 (A = hf regs, B = w2b pre-swizzled global)
        #pragma unroll
        for (int f2t = 0; f2t < 4; ++f2t) {
            f16x8 bw2[4];
            #pragma unroll
            for (int kf = 0; kf < 4; ++kf)
                bw2[kf] = *(const f16x8*)(w2b + (((h * 4 + f2t) * 4 + kf) * 64 + lane) * 8);
            #pragma unroll
            for (int ntile = 0; ntile < 4; ++ntile) {
                f32x4 acc = (f32x4){0.f, 0.f, 0.f, 0.f};
                #pragma unroll
                for (int kf = 0; kf < 4; ++kf)
                    acc = __builtin_amdgcn_mfma_f32_16x16x32_f16(hf[ntile][kf], bw2[kf], acc, 0, 0, 0);
                const int fl = f2t * 16 + lr;                  // node = ntile*16+lq*4+r
                const int g = ntile * 2 + (lq >> 1);
                f16x4 hv;
                #pragma unroll
                for (int r = 0; r < 4; ++r) hv[r] = (f16)acc[r];
                *(f16x4*)&sMain[fl * 64 + ((g ^ (fl & 7)) << 3) + ((lq & 1) * 4)] = hv;
            }
        }
        __syncthreads();

        // E1 (operand-swapped): D[f][i]; per-lane inv2; register max-pool over i
        #pragma unroll
        for (int ftl = 0; ftl < 4; ++ftl) {
            const int fl = ftl * 16 + lr;
            f16x8 b0 = *(const f16x8*)&sMain[fl * 64 + ((lq ^ (fl & 7)) << 3)];
            f16x8 b1 = *(const f16x8*)&sMain[fl * 64 + (((4 + lq) ^ (fl & 7)) << 3)];
            f32x4 mx4 = (f32x4){-1e30f, -1e30f, -1e30f, -1e30f};
            #pragma unroll
            for (int mt = 0; mt < 4; ++mt) {
                f32x4 acc = (f32x4){0.f, 0.f, 0.f, 0.f};
                acc = __builtin_amdgcn_mfma_f32_16x16x32_f16(b0, ap2[mt][0], acc, 0, 0, 0);
                acc = __builtin_amdgcn_mfma_f32_16x16x32_f16(b1, ap2[mt][1], acc, 0, 0, 0);
                #pragma unroll
                for (int r = 0; r < 4; ++r)
                    mx4[r] = fmaxf(mx4[r], acc[r] * inv2[mt]);
            }
            #pragma unroll
            for (int m = 1; m < 16; m <<= 1) {
                #pragma unroll
                for (int r = 0; r < 4; ++r)
                    mx4[r] = fmaxf(mx4[r], __shfl_xor(mx4[r], m, 64));
            }
            if (lr == 0) {
                float4 pv;
                pv.x = elu1(mx4[0]); pv.y = elu1(mx4[1]);
                pv.z = elu1(mx4[2]); pv.w = elu1(mx4[3]);
                *(float4*)&sPool[h * 64 + ftl * 16 + lq * 4] = pv;
            }
        }
        __syncthreads();
    }

    // ================= Readout (per-wave, fp32) =================
    {
        const int o = lane & 31, hh = lane >> 5;
        float s = 0.f;
        #pragma unroll 8
        for (int kk = 0; kk < 64; ++kk) {
            const int c = hh * 64 + kk;
            s = fmaf(sPool[c], mw1[c * 32 + o], s);
        }
        s += __shfl_xor(s, 32, 64);
        s = fmaxf(s + mb1[o], 0.0f);
        if (lane < 32) sHid[lane] = s;
    }
    __syncthreads();
    {
        float sA = mb2[lane], sB = mb2[64 + lane];
        #pragma unroll 8
        for (int q = 0; q < 32; ++q) {
            const float hq = sHid[q];
            sA = fmaf(hq, mw2[q * 128 + lane], sA);
            sB = fmaf(hq, mw2[q * 128 + 64 + lane], sB);
        }
        const float rA = fmaxf(sA, 0.0f) + 1e-6f;   // raw_delta[lane]
        const float rB = fmaxf(sB, 0.0f) + 1e-6f;   // raw_power[lane]
        float sumA = rA, sumB = rB;
        #pragma unroll
        for (int m = 1; m < 64; m <<= 1) {
            sumA += __shfl_xor(sumA, m, 64);
            sumB += __shfl_xor(sumB, m, 64);
        }
        out[b * 64 + lane]        = rB / (sumB + 1e-6f);            // power (PMAX = 1)
        out[OUT2 + b * 64 + lane] = 98.425f * rA / (sumA + 1e-6f);  // delta (Bmax = 98.425)
    }
}

extern "C" void kernel_launch(void* const* d_in, const int* in_sizes, int n_in,
                              void* d_out, int out_size, void* d_ws, size_t ws_size,
                              hipStream_t stream) {
    const float* users = (const float*)d_in[0];
    const float* W1    = (const float*)d_in[1];
    const float* a1    = (const float*)d_in[2];
    const float* W2    = (const float*)d_in[3];
    const float* a2    = (const float*)d_in[4];
    const float* mw1   = (const float*)d_in[5];
    const float* mb1   = (const float*)d_in[6];
    const float* mw2   = (const float*)d_in[7];
    const float* mb2   = (const float*)d_in[8];
    float* out = (float*)d_out;

    f16*   w2b  = (f16*)d_ws;
    float* w1a  = (float*)((char*)d_ws + 32768);
    f16*   w2ab = (f16*)((char*)d_ws + 32800);

    prep<<<64, 256, 0, stream>>>(W2, W1, a1, a2, w2b, w1a, w2ab);
    gat_kernel<<<NBATCH, 64, 0, stream>>>(users, W1, w2b, w1a, w2ab,
                                          mw1, mb1, mw2, mb2, out);
}